// Round 12
// baseline (423.322 us; speedup 1.0000x reference)
//
#include <hip/hip_runtime.h>
#include <hip/hip_bf16.h>
#include <stdint.h>

typedef __attribute__((ext_vector_type(8))) __bf16 bf16x8;
typedef __attribute__((ext_vector_type(2))) __bf16 bf16x2;
typedef __attribute__((ext_vector_type(4))) float floatx4;

#define NB 2
#define SEQ 2048
#define DIN 1024
#define NH 16
#define DH 64
#define DMODEL 1024  // NH*DH
#define BQ 128
#define BK 64
#define PAD 72       // Ps LDS row stride (144 B, 16B-aligned)
#define QSCALE 0.18033688011112042f  // log2(e)/8: folds 1/sqrt(64) and ln2->exp2

__device__ __forceinline__ float bf2f(unsigned short u) {
    return __uint_as_float(((unsigned)u) << 16);
}
__device__ __forceinline__ unsigned short f2bf(float f) {
    unsigned u = __float_as_uint(f);
    unsigned r = (u + 0x7FFFu + ((u >> 16) & 1u)) >> 16;  // RNE
    return (unsigned short)r;
}
__device__ __forceinline__ float ldin(const void* p, size_t idx, int isbf) {
    return isbf ? bf2f(((const unsigned short*)p)[idx]) : ((const float*)p)[idx];
}

// global -> LDS direct DMA, 16 B/lane. LDS dest is wave-uniform base + lane*16.
__device__ __forceinline__ void gl_lds16(const void* g, void* l) {
    __builtin_amdgcn_global_load_lds(
        reinterpret_cast<__attribute__((address_space(1))) unsigned int*>(
            reinterpret_cast<uintptr_t>(g)),
        reinterpret_cast<__attribute__((address_space(3))) unsigned int*>(
            reinterpret_cast<uintptr_t>(l)),
        16, 0, 0);
}

// Per-wave dtype probes (r3/r6-proven, deterministic on pristine inputs)
__device__ __forceinline__ int wave_is_bf16(const void* p) {
    unsigned short u = ((const unsigned short*)p)[2 * (threadIdx.x & 63)];
    int e = (u >> 7) & 0xFF;
    int sane = (u == 0 || (e > 100 && e < 140)) ? 1 : 0;
    return __popcll(__ballot(sane)) >= 32;
}
__device__ __forceinline__ int wave_mask_is_int(const void* p) {
    int v = ((const int*)p)[threadIdx.x & 63];
    int zo = (v == 0 || v == 1) ? 1 : 0;
    return __popcll(__ballot(zo)) >= 48;
}

// ---------------------------------------------------------------------------
// prep: conv_a (acts->bf16) [0,12288) + mask_pack [12288,13312) +
// tiled conv_w (weights->bf16 transposed, coalesced via LDS) [13312,14336)
// r18: weight-section loads vectorized — the 16-iter scalar ldin loop (16
// scalar global + 16 scalar LDS writes/thread over 67 MB of weights) becomes
// 4x float4 (f32) / 4x ushort4+cvt (bf16) + 4x float4 LDS writes.
// ---------------------------------------------------------------------------
__global__ __launch_bounds__(256) void prep(
    const void* __restrict__ q, const void* __restrict__ k, const void* __restrict__ v,
    const void* __restrict__ mask,
    const void* __restrict__ wq, const void* __restrict__ wk,
    const void* __restrict__ wv, const void* __restrict__ wp,
    unsigned short* __restrict__ a0, unsigned short* __restrict__ a1,
    unsigned short* __restrict__ a2,
    unsigned short* __restrict__ t0, unsigned short* __restrict__ t1,
    unsigned short* __restrict__ t2, unsigned short* __restrict__ t3,
    unsigned int* __restrict__ mbits)
{
    __shared__ __align__(16) float xls[64][68];
    const int b = blockIdx.x;
    const int tid = threadIdx.x;
    if (b < 12288) {
        int z = b >> 12, blk = b & 4095;
        const void* src = (z == 0) ? q : (z == 1) ? k : v;
        unsigned short* dst = (z == 0) ? a0 : (z == 1) ? a1 : a2;
        int isbf = wave_is_bf16(src);
        size_t i = ((size_t)blk * 256 + tid) * 4;
        if (isbf) {
            *(ushort4*)&dst[i] = *(const ushort4*)((const unsigned short*)src + i);
        } else {
            float4 f = *(const float4*)((const float*)src + i);
            ushort4 o;
            o.x = f2bf(f.x); o.y = f2bf(f.y); o.z = f2bf(f.z); o.w = f2bf(f.w);
            *(ushort4*)&dst[i] = o;
        }
    } else if (b < 13312) {
        int blk = b - 12288;
        int w = blk * 256 + tid;
        int is_int = wave_mask_is_int(mask);
        unsigned bits = 0;
        if (is_int) {
            const int4* p = (const int4*)mask + (size_t)w * 8;
#pragma unroll
            for (int g = 0; g < 8; ++g) {
                int4 vv = p[g];
                bits |= (unsigned)(vv.x != 0) << (g * 4 + 0);
                bits |= (unsigned)(vv.y != 0) << (g * 4 + 1);
                bits |= (unsigned)(vv.z != 0) << (g * 4 + 2);
                bits |= (unsigned)(vv.w != 0) << (g * 4 + 3);
            }
        } else {
            const uint4* p = (const uint4*)mask + (size_t)w * 2;
#pragma unroll
            for (int g = 0; g < 2; ++g) {
                uint4 vv = p[g];
                unsigned ws4[4] = {vv.x, vv.y, vv.z, vv.w};
#pragma unroll
                for (int c = 0; c < 4; ++c)
#pragma unroll
                    for (int bb = 0; bb < 4; ++bb)
                        bits |= (unsigned)(((ws4[c] >> (8 * bb)) & 0xFFu) != 0)
                                << (g * 16 + c * 4 + bb);
            }
        }
        mbits[w] = bits;
    } else {
        int zb = b - 13312;
        int z = zb >> 8, t = zb & 255;
        const void* src = (z == 0) ? wq : (z == 1) ? wk : (z == 2) ? wv : wp;
        unsigned short* dst = (z == 0) ? t0 : (z == 1) ? t1 : (z == 2) ? t2 : t3;
        int isbf = wave_is_bf16(src);
        int r = tid >> 2, cs = (tid & 3) * 16;

        // vectorized 16-elem row load into xls[r][cs..cs+15] (16B-aligned)
        size_t idx0;
        if (z < 3) {
            int hh = t >> 4, m0 = (t & 15) * 64;
            idx0 = (size_t)hh * 65536 + (size_t)(m0 + r) * 64 + cs;
        } else {
            int m0 = (t >> 4) * 64, c0 = (t & 15) * 64;
            idx0 = (size_t)(m0 + r) * 1024 + c0 + cs;
        }
        float4* xrow = (float4*)&xls[r][cs];
        if (isbf) {
            const unsigned short* sp = (const unsigned short*)src + idx0;
#pragma unroll
            for (int g = 0; g < 4; ++g) {
                ushort4 u = *(const ushort4*)(sp + g * 4);
                float4 f;
                f.x = bf2f(u.x); f.y = bf2f(u.y); f.z = bf2f(u.z); f.w = bf2f(u.w);
                xrow[g] = f;
            }
        } else {
            const float4* fp = (const float4*)((const float*)src + idx0);
#pragma unroll
            for (int g = 0; g < 4; ++g) xrow[g] = fp[g];
        }
        __syncthreads();

        int d2 = tid >> 2, ms = (tid & 3) * 16;
        size_t orow;
        if (z < 3) {
            int hh = t >> 4, m0 = (t & 15) * 64;
            orow = (size_t)(hh * 64 + d2) * 1024 + m0 + ms;
        } else {
            int m0 = (t >> 4) * 64, c0 = (t & 15) * 64;
            orow = (size_t)(c0 + d2) * 1024 + m0 + ms;
        }
#pragma unroll
        for (int g = 0; g < 4; ++g) {
            ushort4 o;
            o.x = f2bf(xls[ms + g * 4 + 0][d2]);
            o.y = f2bf(xls[ms + g * 4 + 1][d2]);
            o.z = f2bf(xls[ms + g * 4 + 2][d2]);
            o.w = f2bf(xls[ms + g * 4 + 3][d2]);
            *(ushort4*)&dst[orow + g * 4] = o;
        }
    }
}

// ---------------------------------------------------------------------------
// Unified MFMA GEMM with global_load_lds staging (r9). mode: 0 Q (prescaled
// QSCALE)->(n,h,k,d); 1 K; 2 V->(n,h,d,k) LDS-transposed; 3 OUT.
// r17: XCD-aware tile swizzle (T1), bijective within each 256-block z-slice.
// ---------------------------------------------------------------------------
__global__ __launch_bounds__(256) void gemm_mfma(
    const unsigned short* __restrict__ A0, const unsigned short* __restrict__ A1,
    const unsigned short* __restrict__ A2,
    const unsigned short* __restrict__ B0, const unsigned short* __restrict__ B1,
    const unsigned short* __restrict__ B2,
    const void* __restrict__ bias0, const void* __restrict__ bias1,
    const void* __restrict__ bias2,
    void* __restrict__ C0, void* __restrict__ C1, void* __restrict__ C2,
    int mode0)
{
    const int z = blockIdx.z;
    const unsigned short* A  = (z == 0) ? A0 : (z == 1) ? A1 : A2;
    const unsigned short* BT = (z == 0) ? B0 : (z == 1) ? B1 : B2;
    const void* bias = (z == 0) ? bias0 : (z == 1) ? bias1 : bias2;
    void* C = (z == 0) ? C0 : (z == 1) ? C1 : C2;
    const int mode = mode0 + z;
    const int isbf = wave_is_bf16(bias);
    const float scl = (mode == 0) ? QSCALE : 1.0f;

    const int lin  = blockIdx.x + (blockIdx.y << 3);   // 0..255
    const int xcd8 = lin & 7, loc = lin >> 3;          // loc 0..31
    const int n0   = (loc & 7) * 128;
    const int m0g  = ((xcd8 << 2) + (loc >> 3)) * 128;

    const int tid = threadIdx.x;
    const int wave = tid >> 6, lane = tid & 63;
    const int l16 = lane & 15, quad = lane >> 4;
    const int wm = wave & 1, wn = wave >> 1;

    __shared__ __align__(16) unsigned short smem[17408];
    unsigned short* As = smem;
    unsigned short* Bs = smem + 8192;

    floatx4 acc[4][4];
#pragma unroll
    for (int mt = 0; mt < 4; ++mt)
#pragma unroll
        for (int nt = 0; nt < 4; ++nt) acc[mt][nt] = floatx4{0.f, 0.f, 0.f, 0.f};

    const int lrow8 = lane >> 3;
    const int lseg  = (lane & 7) * 8;

    for (int kk = 0; kk < 1024; kk += 64) {
#pragma unroll
        for (int j = 0; j < 4; ++j) {
            int row0 = wave * 8 + j * 32;
            gl_lds16(&A[(size_t)(m0g + row0 + lrow8) * 1024 + kk + lseg], &As[row0 * 64]);
            gl_lds16(&BT[(size_t)(n0 + row0 + lrow8) * 1024 + kk + lseg], &Bs[row0 * 64]);
        }
        __syncthreads();
#pragma unroll
        for (int ks = 0; ks < 2; ++ks) {
            bf16x8 af[4], bf[4];
#pragma unroll
            for (int mt = 0; mt < 4; ++mt)
                af[mt] = *(const bf16x8*)&As[(wm * 64 + mt * 16 + l16) * 64 + ks * 32 + quad * 8];
#pragma unroll
            for (int nt = 0; nt < 4; ++nt)
                bf[nt] = *(const bf16x8*)&Bs[(wn * 64 + nt * 16 + l16) * 64 + ks * 32 + quad * 8];
#pragma unroll
            for (int mt = 0; mt < 4; ++mt)
#pragma unroll
                for (int nt = 0; nt < 4; ++nt)
                    acc[mt][nt] = __builtin_amdgcn_mfma_f32_16x16x32_bf16(af[mt], bf[nt], acc[mt][nt], 0, 0, 0);
        }
        __syncthreads();
    }

    float bv4[4];
#pragma unroll
    for (int nt = 0; nt < 4; ++nt)
        bv4[nt] = ldin(bias, n0 + wn * 64 + nt * 16 + l16, isbf);

    if (mode <= 1) {  // Q/K -> (n,h,k,d)
        unsigned short* O = (unsigned short*)C;
#pragma unroll
        for (int mt = 0; mt < 4; ++mt)
#pragma unroll
            for (int reg = 0; reg < 4; ++reg) {
                int row = m0g + wm * 64 + mt * 16 + quad * 4 + reg;
                int nb = row >> 11, kq = row & (SEQ - 1);
#pragma unroll
                for (int nt = 0; nt < 4; ++nt) {
                    int c = n0 + wn * 64 + nt * 16 + l16;
                    int h = c >> 6, d = c & 63;
                    O[(((size_t)nb * NH + h) * SEQ + kq) * DH + d] =
                        f2bf((acc[mt][nt][reg] + bv4[nt]) * scl);
                }
            }
    } else if (mode == 2) {  // V -> (n,h,d,k) via LDS transpose
#pragma unroll
        for (int mt = 0; mt < 4; ++mt)
#pragma unroll
            for (int nt = 0; nt < 4; ++nt)
#pragma unroll
                for (int reg = 0; reg < 4; ++reg) {
                    int m_l = wm * 64 + mt * 16 + quad * 4 + reg;
                    int c_l = wn * 64 + nt * 16 + l16;
                    smem[c_l * 136 + m_l] = f2bf(acc[mt][nt][reg] + bv4[nt]);
                }
        __syncthreads();
        unsigned short* O = (unsigned short*)C;
        int nb = m0g >> 11;
        int kq0 = m0g & (SEQ - 1);
#pragma unroll
        for (int j = 0; j < 8; ++j) {
            int i = tid + j * 256;
            int c_l = i >> 4, m8 = (i & 15) * 8;
            int cg = n0 + c_l, h = cg >> 6, d = cg & 63;
            *(bf16x8*)&O[(((size_t)nb * NH + h) * DH + d) * SEQ + kq0 + m8] =
                *(const bf16x8*)&smem[c_l * 136 + m8];
        }
    } else {  // OUT row-major, dual dtype
        unsigned short* Ob = (unsigned short*)C;
        float* Of = (float*)C;
#pragma unroll
        for (int mt = 0; mt < 4; ++mt)
#pragma unroll
            for (int reg = 0; reg < 4; ++reg) {
                int row = m0g + wm * 64 + mt * 16 + quad * 4 + reg;
#pragma unroll
                for (int nt = 0; nt < 4; ++nt) {
                    int c = n0 + wn * 64 + nt * 16 + l16;
                    float v = acc[mt][nt][reg] + bv4[nt];
                    if (isbf) Ob[(size_t)row * DMODEL + c] = f2bf(v);
                    else      Of[(size_t)row * DMODEL + c] = v;
                }
            }
    }
}

// ---------------------------------------------------------------------------
// MFMA flash attention. r18: DOUBLE buffer (was triple) to unlock 3 blocks/CU.
// Evidence: r15 proved counted-vmcnt vs full-drain is NULL (the drain costs
// nothing), r16 proved occupancy is worth ~4%/doubling. So the 3rd buffer was
// pure LDS waste: 67584 B capped us at 2 blocks/CU (4 waves/SIMD). Dbuf +
// 1-ahead staging + vmcnt(0)+barrier = 51200 B -> 3 blocks/CU = 6 waves/SIMD
// (+50% occupancy) at zero pipeline cost. Keeps r17's static unroll (by 2),
// setprio, XCD swizzle, mbits masking, ones-MFMA row-sum.
// ---------------------------------------------------------------------------
__global__ __launch_bounds__(512, 6) void attn_mfma(
    const unsigned short* __restrict__ qws, const unsigned short* __restrict__ kws,
    const unsigned short* __restrict__ vtws, const unsigned int* __restrict__ mbits,
    unsigned short* __restrict__ yws)
{
    // XCD-aware remap (r13-proven): 64 blocks/XCD = 4 (n,h) x 16 qt.
    const int linear = blockIdx.x + (blockIdx.y << 4) + (blockIdx.z << 8);
    const int xcd = linear & 7, loc = linear >> 3;
    const int hn  = (xcd << 2) + (loc >> 4);   // 0..31
    const int qt  = loc & 15;
    const int h   = hn & 15;
    const int n   = hn >> 4;

    const int tid  = threadIdx.x;
    const int wave = tid >> 6;          // 0..7
    const int lane = tid & 63;
    const int l16  = lane & 15;
    const int quad = lane >> 4;

    __shared__ __align__(16) unsigned short Ks[2][BK * DH];    // [key][d], swizzled
    __shared__ __align__(16) unsigned short VTs[2][DH * BK];   // [d][key], swizzled
    __shared__ __align__(16) unsigned short Ps[8][16 * PAD];   // per-wave [qrow][key]

    const size_t base_nh = ((size_t)n * NH + h) * SEQ * DH;
    const size_t base_vt = ((size_t)n * NH + h) * DH * SEQ;
    const int q0 = qt * BQ;
    const int qrow = wave * 16 + l16;   // this lane's q-row within the block

    // mask-bit row pointer + Q fragments (prescaled QSCALE)
    const unsigned int* mr0 = mbits + ((size_t)n * SEQ + q0 + qrow) * (SEQ / 32);
    bf16x8 af[2];
    {
        const unsigned short* qp = qws + base_nh + (size_t)(q0 + qrow) * DH + quad * 8;
        af[0] = *(const bf16x8*)qp;
        af[1] = *(const bf16x8*)(qp + 32);
    }

    // DMA staging geometry + XOR swizzle (r9-proven). Each wave stages 8 rows
    // of K and 8 rows of V^T per tile (8 waves x 8 = 64 rows each).
    const int srow8  = lane >> 3;
    const int schunk = ((lane & 7) ^ srow8) * 8;
    const int swz = l16 & 7;
    int koff[2], voff[2];
#pragma unroll
    for (int ks = 0; ks < 2; ++ks) {
        koff[ks] = l16 * DH + (((ks * 4 + quad) ^ swz) * 8);
        voff[ks] = l16 * BK + (((ks * 4 + quad) ^ swz) * 8);
    }

    // ones B-fragment for the row-sum MFMA
    bf16x8 vones;
#pragma unroll
    for (int j = 0; j < 8; ++j) vones[j] = (__bf16)1.0f;

    // stage tile `t` into buffer slot `b` (2 VMEM ops/wave)
    auto stage = [&](int b, int t) {
        int j0t = t * BK;
        int rl = wave * 8;
        gl_lds16(&kws[base_nh + (size_t)(j0t + rl + srow8) * DH + schunk], &Ks[b][rl * DH]);
        gl_lds16(&vtws[base_vt + (size_t)(rl + srow8) * SEQ + j0t + schunk], &VTs[b][rl * BK]);
    };

    floatx4 O[4];
#pragma unroll
    for (int dt = 0; dt < 4; ++dt) O[dt] = floatx4{0.f, 0.f, 0.f, 0.f};
    floatx4 Lacc = floatx4{0.f, 0.f, 0.f, 0.f};

    // prologue: stage tile 0 into buf 0; mask for tile 0
    stage(0, 0);
    uint2 mwC = *(const uint2*)&mr0[0];
    asm volatile("s_waitcnt vmcnt(0)" ::: "memory");
    __builtin_amdgcn_s_barrier();

    // one tile iteration. cb is ALWAYS a literal at call sites -> constant-
    // folded after inlining (static LDS bases). 1-ahead staging into cb^1;
    // syncmode: 0 = vmcnt(0)+barrier (certifies tile it+1), 2 = none (last).
    auto body = [&](int it, int cb, bool do_stage, int syncmode) {
        uint2 nA = {0, 0};
        if (do_stage) {
            stage(cb ^ 1, it + 1);
            nA = *(const uint2*)&mr0[(it + 1) * 2];
        }

        // ---- K·Q^T on buffer cb ----
        bf16x8 bfK[4][2];
#pragma unroll
        for (int nt = 0; nt < 4; ++nt)
#pragma unroll
            for (int ks = 0; ks < 2; ++ks)
                bfK[nt][ks] = *(const bf16x8*)&Ks[cb][nt * 16 * DH + koff[ks]];

        float St[4][4];
        __builtin_amdgcn_s_setprio(1);
#pragma unroll
        for (int nt = 0; nt < 4; ++nt) {
            floatx4 c = {0.f, 0.f, 0.f, 0.f};
            c = __builtin_amdgcn_mfma_f32_16x16x32_bf16(bfK[nt][0], af[0], c, 0, 0, 0);
            c = __builtin_amdgcn_mfma_f32_16x16x32_bf16(bfK[nt][1], af[1], c, 0, 0, 0);
            St[nt][0] = c[0]; St[nt][1] = c[1]; St[nt][2] = c[2]; St[nt][3] = c[3];
        }
        __builtin_amdgcn_s_setprio(0);

        // ---- p = bit ? 0 : exp2(s), RNE bf16 pack, b64 store ----
#pragma unroll
        for (int nt = 0; nt < 4; ++nt) {
            unsigned w = (nt & 2) ? mwC.y : mwC.x;
            int bb = (nt & 1) * 16 + quad * 4;
            float p[4];
#pragma unroll
            for (int r = 0; r < 4; ++r) {
                float e = __builtin_amdgcn_exp2f(St[nt][r]);
                p[r] = ((w >> (bb + r)) & 1u) ? 0.f : e;
            }
            bf16x2 e01, e23;
            e01[0] = (__bf16)p[0]; e01[1] = (__bf16)p[1];
            e23[0] = (__bf16)p[2]; e23[1] = (__bf16)p[3];
            uint2 pk;
            pk.x = *(unsigned*)&e01;
            pk.y = *(unsigned*)&e23;
            *(uint2*)&Ps[wave][l16 * PAD + nt * 16 + quad * 4] = pk;
        }

        // ---- PV + row-sum MFMA ----
        bf16x8 pa[2], vb[4][2];
#pragma unroll
        for (int ks = 0; ks < 2; ++ks)
            pa[ks] = *(const bf16x8*)&Ps[wave][l16 * PAD + ks * 32 + quad * 8];
#pragma unroll
        for (int dt = 0; dt < 4; ++dt)
#pragma unroll
            for (int ks = 0; ks < 2; ++ks)
                vb[dt][ks] = *(const bf16x8*)&VTs[cb][dt * 16 * BK + voff[ks]];

        __builtin_amdgcn_s_setprio(1);
        Lacc = __builtin_amdgcn_mfma_f32_16x16x32_bf16(pa[0], vones, Lacc, 0, 0, 0);
        Lacc = __builtin_amdgcn_mfma_f32_16x16x32_bf16(pa[1], vones, Lacc, 0, 0, 0);
#pragma unroll
        for (int dt = 0; dt < 4; ++dt) {
            O[dt] = __builtin_amdgcn_mfma_f32_16x16x32_bf16(pa[0], vb[dt][0], O[dt], 0, 0, 0);
            O[dt] = __builtin_amdgcn_mfma_f32_16x16x32_bf16(pa[1], vb[dt][1], O[dt], 0, 0, 0);
        }
        __builtin_amdgcn_s_setprio(0);

        if (syncmode == 0) {
            asm volatile("s_waitcnt vmcnt(0)" ::: "memory");
            __builtin_amdgcn_s_barrier();
        }
        mwC = nA;
    };

    // 32 iterations, buffer parity cb = it & 1 (static at each call site).
    // Iter `it` stages tile it+1 into cb^1; barrier certifies it for it+1.
    for (int t2 = 0; t2 < 30; t2 += 2) {
        body(t2 + 0, 0, true, 0);
        body(t2 + 1, 1, true, 0);
    }
    body(30, 0, true, 0);    // stages tile 31 into buf 1; drain + barrier
    body(31, 1, false, 2);   // last tile, no stage, no sync

    // epilogue: Lacc holds full row-sums in (quad*4+r) layout
#pragma unroll
    for (int r = 0; r < 4; ++r) {
        float lr = Lacc[r];
        float inv = (lr > 0.f) ? 1.f / lr : 0.f;
        int row = q0 + wave * 16 + quad * 4 + r;
#pragma unroll
        for (int dt = 0; dt < 4; ++dt) {
            int col = h * DH + dt * 16 + l16;
            yws[((size_t)n * SEQ + row) * DMODEL + col] = f2bf(O[dt][r] * inv);
        }
    }
}

extern "C" void kernel_launch(void* const* d_in, const int* in_sizes, int n_in,
                              void* d_out, int out_size, void* d_ws, size_t ws_size,
                              hipStream_t stream) {
    const void* query = d_in[0];
    const void* key_  = d_in[1];
    const void* value = d_in[2];
    const void* mask  = d_in[3];
    const void* Wq = d_in[4];
    const void* bq = d_in[5];
    const void* Wk = d_in[6];
    const void* bk = d_in[7];
    const void* Wv = d_in[8];
    const void* bv = d_in[9];
    const void* Wp = d_in[10];
    const void* bp = d_in[11];

    const size_t per = (size_t)NB * NH * SEQ * DH;  // 4,194,304
    unsigned short* us = (unsigned short*)d_ws;
    unsigned short* qws  = us;
    unsigned short* kws  = us + per;
    unsigned short* vtws = us + 2 * per;
    unsigned short* abf0 = us + 3 * per;   // bf16 query acts; reused as yws after proj
    unsigned short* abf1 = us + 4 * per;
    unsigned short* abf2 = us + 5 * per;
    unsigned short* wt0  = us + 6 * per;
    unsigned short* wt1  = wt0 + 1048576;
    unsigned short* wt2  = wt1 + 1048576;
    unsigned short* wt3  = wt2 + 1048576;
    unsigned int* mbits  = (unsigned int*)(wt3 + 1048576);  // 262144 words
    unsigned short* yws = abf0;

    prep<<<dim3(14336), 256, 0, stream>>>(query, key_, value, mask,
                                          Wq, Wk, Wv, Wp,
                                          abf0, abf1, abf2,
                                          wt0, wt1, wt2, wt3, mbits);
    gemm_mfma<<<dim3(8, 32, 3), 256, 0, stream>>>(abf0, abf1, abf2, wt0, wt1, wt2,
                                                  bq, bk, bv, qws, kws, vtws, 0);
    attn_mfma<<<dim3(SEQ / BQ, NH, NB), 512, 0, stream>>>(qws, kws, vtws, mbits, yws);
    gemm_mfma<<<dim3(8, 32, 1), 256, 0, stream>>>(yws, yws, yws, wt3, wt3, wt3,
                                                  bp, bp, bp, d_out, d_out, d_out, 3);
}

// Round 13
// 277.722 us; speedup vs baseline: 1.5243x; 1.5243x over previous
//
#include <hip/hip_runtime.h>
#include <hip/hip_bf16.h>
#include <stdint.h>

typedef __attribute__((ext_vector_type(8))) __bf16 bf16x8;
typedef __attribute__((ext_vector_type(2))) __bf16 bf16x2;
typedef __attribute__((ext_vector_type(4))) float floatx4;

#define NB 2
#define SEQ 2048
#define DIN 1024
#define NH 16
#define DH 64
#define DMODEL 1024  // NH*DH
#define BQ 128
#define BK 64
#define PAD 72       // Ps LDS row stride (144 B, 16B-aligned)
#define QSCALE 0.18033688011112042f  // log2(e)/8: folds 1/sqrt(64) and ln2->exp2

__device__ __forceinline__ float bf2f(unsigned short u) {
    return __uint_as_float(((unsigned)u) << 16);
}
__device__ __forceinline__ unsigned short f2bf(float f) {
    unsigned u = __float_as_uint(f);
    unsigned r = (u + 0x7FFFu + ((u >> 16) & 1u)) >> 16;  // RNE
    return (unsigned short)r;
}
__device__ __forceinline__ float ldin(const void* p, size_t idx, int isbf) {
    return isbf ? bf2f(((const unsigned short*)p)[idx]) : ((const float*)p)[idx];
}

// global -> LDS direct DMA, 16 B/lane. LDS dest is wave-uniform base + lane*16.
__device__ __forceinline__ void gl_lds16(const void* g, void* l) {
    __builtin_amdgcn_global_load_lds(
        reinterpret_cast<__attribute__((address_space(1))) unsigned int*>(
            reinterpret_cast<uintptr_t>(g)),
        reinterpret_cast<__attribute__((address_space(3))) unsigned int*>(
            reinterpret_cast<uintptr_t>(l)),
        16, 0, 0);
}

// Per-wave dtype probes (r3/r6-proven, deterministic on pristine inputs)
__device__ __forceinline__ int wave_is_bf16(const void* p) {
    unsigned short u = ((const unsigned short*)p)[2 * (threadIdx.x & 63)];
    int e = (u >> 7) & 0xFF;
    int sane = (u == 0 || (e > 100 && e < 140)) ? 1 : 0;
    return __popcll(__ballot(sane)) >= 32;
}
__device__ __forceinline__ int wave_mask_is_int(const void* p) {
    int v = ((const int*)p)[threadIdx.x & 63];
    int zo = (v == 0 || v == 1) ? 1 : 0;
    return __popcll(__ballot(zo)) >= 48;
}

// ---------------------------------------------------------------------------
// prep: conv_a (acts->bf16) [0,12288) + mask_pack [12288,13312) +
// tiled conv_w (weights->bf16 transposed, coalesced via LDS) [13312,14336)
// r18: weight-section loads vectorized (4x float4 / 4x ushort4+cvt).
// ---------------------------------------------------------------------------
__global__ __launch_bounds__(256) void prep(
    const void* __restrict__ q, const void* __restrict__ k, const void* __restrict__ v,
    const void* __restrict__ mask,
    const void* __restrict__ wq, const void* __restrict__ wk,
    const void* __restrict__ wv, const void* __restrict__ wp,
    unsigned short* __restrict__ a0, unsigned short* __restrict__ a1,
    unsigned short* __restrict__ a2,
    unsigned short* __restrict__ t0, unsigned short* __restrict__ t1,
    unsigned short* __restrict__ t2, unsigned short* __restrict__ t3,
    unsigned int* __restrict__ mbits)
{
    __shared__ __align__(16) float xls[64][68];
    const int b = blockIdx.x;
    const int tid = threadIdx.x;
    if (b < 12288) {
        int z = b >> 12, blk = b & 4095;
        const void* src = (z == 0) ? q : (z == 1) ? k : v;
        unsigned short* dst = (z == 0) ? a0 : (z == 1) ? a1 : a2;
        int isbf = wave_is_bf16(src);
        size_t i = ((size_t)blk * 256 + tid) * 4;
        if (isbf) {
            *(ushort4*)&dst[i] = *(const ushort4*)((const unsigned short*)src + i);
        } else {
            float4 f = *(const float4*)((const float*)src + i);
            ushort4 o;
            o.x = f2bf(f.x); o.y = f2bf(f.y); o.z = f2bf(f.z); o.w = f2bf(f.w);
            *(ushort4*)&dst[i] = o;
        }
    } else if (b < 13312) {
        int blk = b - 12288;
        int w = blk * 256 + tid;
        int is_int = wave_mask_is_int(mask);
        unsigned bits = 0;
        if (is_int) {
            const int4* p = (const int4*)mask + (size_t)w * 8;
#pragma unroll
            for (int g = 0; g < 8; ++g) {
                int4 vv = p[g];
                bits |= (unsigned)(vv.x != 0) << (g * 4 + 0);
                bits |= (unsigned)(vv.y != 0) << (g * 4 + 1);
                bits |= (unsigned)(vv.z != 0) << (g * 4 + 2);
                bits |= (unsigned)(vv.w != 0) << (g * 4 + 3);
            }
        } else {
            const uint4* p = (const uint4*)mask + (size_t)w * 2;
#pragma unroll
            for (int g = 0; g < 2; ++g) {
                uint4 vv = p[g];
                unsigned ws4[4] = {vv.x, vv.y, vv.z, vv.w};
#pragma unroll
                for (int c = 0; c < 4; ++c)
#pragma unroll
                    for (int bb = 0; bb < 4; ++bb)
                        bits |= (unsigned)(((ws4[c] >> (8 * bb)) & 0xFFu) != 0)
                                << (g * 16 + c * 4 + bb);
            }
        }
        mbits[w] = bits;
    } else {
        int zb = b - 13312;
        int z = zb >> 8, t = zb & 255;
        const void* src = (z == 0) ? wq : (z == 1) ? wk : (z == 2) ? wv : wp;
        unsigned short* dst = (z == 0) ? t0 : (z == 1) ? t1 : (z == 2) ? t2 : t3;
        int isbf = wave_is_bf16(src);
        int r = tid >> 2, cs = (tid & 3) * 16;

        // vectorized 16-elem row load into xls[r][cs..cs+15] (16B-aligned)
        size_t idx0;
        if (z < 3) {
            int hh = t >> 4, m0 = (t & 15) * 64;
            idx0 = (size_t)hh * 65536 + (size_t)(m0 + r) * 64 + cs;
        } else {
            int m0 = (t >> 4) * 64, c0 = (t & 15) * 64;
            idx0 = (size_t)(m0 + r) * 1024 + c0 + cs;
        }
        float4* xrow = (float4*)&xls[r][cs];
        if (isbf) {
            const unsigned short* sp = (const unsigned short*)src + idx0;
#pragma unroll
            for (int g = 0; g < 4; ++g) {
                ushort4 u = *(const ushort4*)(sp + g * 4);
                float4 f;
                f.x = bf2f(u.x); f.y = bf2f(u.y); f.z = bf2f(u.z); f.w = bf2f(u.w);
                xrow[g] = f;
            }
        } else {
            const float4* fp = (const float4*)((const float*)src + idx0);
#pragma unroll
            for (int g = 0; g < 4; ++g) xrow[g] = fp[g];
        }
        __syncthreads();

        int d2 = tid >> 2, ms = (tid & 3) * 16;
        size_t orow;
        if (z < 3) {
            int hh = t >> 4, m0 = (t & 15) * 64;
            orow = (size_t)(hh * 64 + d2) * 1024 + m0 + ms;
        } else {
            int m0 = (t >> 4) * 64, c0 = (t & 15) * 64;
            orow = (size_t)(c0 + d2) * 1024 + m0 + ms;
        }
#pragma unroll
        for (int g = 0; g < 4; ++g) {
            ushort4 o;
            o.x = f2bf(xls[ms + g * 4 + 0][d2]);
            o.y = f2bf(xls[ms + g * 4 + 1][d2]);
            o.z = f2bf(xls[ms + g * 4 + 2][d2]);
            o.w = f2bf(xls[ms + g * 4 + 3][d2]);
            *(ushort4*)&dst[orow + g * 4] = o;
        }
    }
}

// ---------------------------------------------------------------------------
// Unified MFMA GEMM with global_load_lds staging (r9). mode: 0 Q (prescaled
// QSCALE)->(n,h,k,d); 1 K; 2 V->(n,h,d,k) LDS-transposed; 3 OUT.
// r17: XCD-aware tile swizzle (T1), bijective within each 256-block z-slice.
// ---------------------------------------------------------------------------
__global__ __launch_bounds__(256) void gemm_mfma(
    const unsigned short* __restrict__ A0, const unsigned short* __restrict__ A1,
    const unsigned short* __restrict__ A2,
    const unsigned short* __restrict__ B0, const unsigned short* __restrict__ B1,
    const unsigned short* __restrict__ B2,
    const void* __restrict__ bias0, const void* __restrict__ bias1,
    const void* __restrict__ bias2,
    void* __restrict__ C0, void* __restrict__ C1, void* __restrict__ C2,
    int mode0)
{
    const int z = blockIdx.z;
    const unsigned short* A  = (z == 0) ? A0 : (z == 1) ? A1 : A2;
    const unsigned short* BT = (z == 0) ? B0 : (z == 1) ? B1 : B2;
    const void* bias = (z == 0) ? bias0 : (z == 1) ? bias1 : bias2;
    void* C = (z == 0) ? C0 : (z == 1) ? C1 : C2;
    const int mode = mode0 + z;
    const int isbf = wave_is_bf16(bias);
    const float scl = (mode == 0) ? QSCALE : 1.0f;

    const int lin  = blockIdx.x + (blockIdx.y << 3);   // 0..255
    const int xcd8 = lin & 7, loc = lin >> 3;          // loc 0..31
    const int n0   = (loc & 7) * 128;
    const int m0g  = ((xcd8 << 2) + (loc >> 3)) * 128;

    const int tid = threadIdx.x;
    const int wave = tid >> 6, lane = tid & 63;
    const int l16 = lane & 15, quad = lane >> 4;
    const int wm = wave & 1, wn = wave >> 1;

    __shared__ __align__(16) unsigned short smem[17408];
    unsigned short* As = smem;
    unsigned short* Bs = smem + 8192;

    floatx4 acc[4][4];
#pragma unroll
    for (int mt = 0; mt < 4; ++mt)
#pragma unroll
        for (int nt = 0; nt < 4; ++nt) acc[mt][nt] = floatx4{0.f, 0.f, 0.f, 0.f};

    const int lrow8 = lane >> 3;
    const int lseg  = (lane & 7) * 8;

    for (int kk = 0; kk < 1024; kk += 64) {
#pragma unroll
        for (int j = 0; j < 4; ++j) {
            int row0 = wave * 8 + j * 32;
            gl_lds16(&A[(size_t)(m0g + row0 + lrow8) * 1024 + kk + lseg], &As[row0 * 64]);
            gl_lds16(&BT[(size_t)(n0 + row0 + lrow8) * 1024 + kk + lseg], &Bs[row0 * 64]);
        }
        __syncthreads();
#pragma unroll
        for (int ks = 0; ks < 2; ++ks) {
            bf16x8 af[4], bf[4];
#pragma unroll
            for (int mt = 0; mt < 4; ++mt)
                af[mt] = *(const bf16x8*)&As[(wm * 64 + mt * 16 + l16) * 64 + ks * 32 + quad * 8];
#pragma unroll
            for (int nt = 0; nt < 4; ++nt)
                bf[nt] = *(const bf16x8*)&Bs[(wn * 64 + nt * 16 + l16) * 64 + ks * 32 + quad * 8];
#pragma unroll
            for (int mt = 0; mt < 4; ++mt)
#pragma unroll
                for (int nt = 0; nt < 4; ++nt)
                    acc[mt][nt] = __builtin_amdgcn_mfma_f32_16x16x32_bf16(af[mt], bf[nt], acc[mt][nt], 0, 0, 0);
        }
        __syncthreads();
    }

    float bv4[4];
#pragma unroll
    for (int nt = 0; nt < 4; ++nt)
        bv4[nt] = ldin(bias, n0 + wn * 64 + nt * 16 + l16, isbf);

    if (mode <= 1) {  // Q/K -> (n,h,k,d)
        unsigned short* O = (unsigned short*)C;
#pragma unroll
        for (int mt = 0; mt < 4; ++mt)
#pragma unroll
            for (int reg = 0; reg < 4; ++reg) {
                int row = m0g + wm * 64 + mt * 16 + quad * 4 + reg;
                int nb = row >> 11, kq = row & (SEQ - 1);
#pragma unroll
                for (int nt = 0; nt < 4; ++nt) {
                    int c = n0 + wn * 64 + nt * 16 + l16;
                    int h = c >> 6, d = c & 63;
                    O[(((size_t)nb * NH + h) * SEQ + kq) * DH + d] =
                        f2bf((acc[mt][nt][reg] + bv4[nt]) * scl);
                }
            }
    } else if (mode == 2) {  // V -> (n,h,d,k) via LDS transpose
#pragma unroll
        for (int mt = 0; mt < 4; ++mt)
#pragma unroll
            for (int nt = 0; nt < 4; ++nt)
#pragma unroll
                for (int reg = 0; reg < 4; ++reg) {
                    int m_l = wm * 64 + mt * 16 + quad * 4 + reg;
                    int c_l = wn * 64 + nt * 16 + l16;
                    smem[c_l * 136 + m_l] = f2bf(acc[mt][nt][reg] + bv4[nt]);
                }
        __syncthreads();
        unsigned short* O = (unsigned short*)C;
        int nb = m0g >> 11;
        int kq0 = m0g & (SEQ - 1);
#pragma unroll
        for (int j = 0; j < 8; ++j) {
            int i = tid + j * 256;
            int c_l = i >> 4, m8 = (i & 15) * 8;
            int cg = n0 + c_l, h = cg >> 6, d = cg & 63;
            *(bf16x8*)&O[(((size_t)nb * NH + h) * DH + d) * SEQ + kq0 + m8] =
                *(const bf16x8*)&smem[c_l * 136 + m8];
        }
    } else {  // OUT row-major, dual dtype
        unsigned short* Ob = (unsigned short*)C;
        float* Of = (float*)C;
#pragma unroll
        for (int mt = 0; mt < 4; ++mt)
#pragma unroll
            for (int reg = 0; reg < 4; ++reg) {
                int row = m0g + wm * 64 + mt * 16 + quad * 4 + reg;
#pragma unroll
                for (int nt = 0; nt < 4; ++nt) {
                    int c = n0 + wn * 64 + nt * 16 + l16;
                    float v = acc[mt][nt][reg] + bv4[nt];
                    if (isbf) Ob[(size_t)row * DMODEL + c] = f2bf(v);
                    else      Of[(size_t)row * DMODEL + c] = v;
                }
            }
    }
}

// ---------------------------------------------------------------------------
// MFMA flash attention. r19: r18's double-buffer WITHOUT the launch_bounds
// register squeeze. r18 post-mortem: __launch_bounds__(512,6) forced VGPR
// 60->40, spilling the inner loop to scratch (FETCH 14->384 MB, WRITE 8->409
// MB, attn 60->207 us). At the natural ~60 VGPR, 6 waves/SIMD needs only
// VGPR<=85 — no coercion required; LDS was the only limiter and dbuf fixed
// it (51200 B x 3 = 153.6 KB < 160 KB -> 3 blocks/CU). So: (512,4) bound
// (r17-proven), dbuf + 1-ahead staging + vmcnt(0)+barrier (r15 proved
// counted-vmcnt is NULL), static unroll-by-2, setprio, XCD swizzle.
// ---------------------------------------------------------------------------
__global__ __launch_bounds__(512, 4) void attn_mfma(
    const unsigned short* __restrict__ qws, const unsigned short* __restrict__ kws,
    const unsigned short* __restrict__ vtws, const unsigned int* __restrict__ mbits,
    unsigned short* __restrict__ yws)
{
    // XCD-aware remap (r13-proven): 64 blocks/XCD = 4 (n,h) x 16 qt.
    const int linear = blockIdx.x + (blockIdx.y << 4) + (blockIdx.z << 8);
    const int xcd = linear & 7, loc = linear >> 3;
    const int hn  = (xcd << 2) + (loc >> 4);   // 0..31
    const int qt  = loc & 15;
    const int h   = hn & 15;
    const int n   = hn >> 4;

    const int tid  = threadIdx.x;
    const int wave = tid >> 6;          // 0..7
    const int lane = tid & 63;
    const int l16  = lane & 15;
    const int quad = lane >> 4;

    __shared__ __align__(16) unsigned short Ks[2][BK * DH];    // [key][d], swizzled
    __shared__ __align__(16) unsigned short VTs[2][DH * BK];   // [d][key], swizzled
    __shared__ __align__(16) unsigned short Ps[8][16 * PAD];   // per-wave [qrow][key]

    const size_t base_nh = ((size_t)n * NH + h) * SEQ * DH;
    const size_t base_vt = ((size_t)n * NH + h) * DH * SEQ;
    const int q0 = qt * BQ;
    const int qrow = wave * 16 + l16;   // this lane's q-row within the block

    // mask-bit row pointer + Q fragments (prescaled QSCALE)
    const unsigned int* mr0 = mbits + ((size_t)n * SEQ + q0 + qrow) * (SEQ / 32);
    bf16x8 af[2];
    {
        const unsigned short* qp = qws + base_nh + (size_t)(q0 + qrow) * DH + quad * 8;
        af[0] = *(const bf16x8*)qp;
        af[1] = *(const bf16x8*)(qp + 32);
    }

    // DMA staging geometry + XOR swizzle (r9-proven). Each wave stages 8 rows
    // of K and 8 rows of V^T per tile (8 waves x 8 = 64 rows each).
    const int srow8  = lane >> 3;
    const int schunk = ((lane & 7) ^ srow8) * 8;
    const int swz = l16 & 7;
    int koff[2], voff[2];
#pragma unroll
    for (int ks = 0; ks < 2; ++ks) {
        koff[ks] = l16 * DH + (((ks * 4 + quad) ^ swz) * 8);
        voff[ks] = l16 * BK + (((ks * 4 + quad) ^ swz) * 8);
    }

    // ones B-fragment for the row-sum MFMA
    bf16x8 vones;
#pragma unroll
    for (int j = 0; j < 8; ++j) vones[j] = (__bf16)1.0f;

    // stage tile `t` into buffer slot `b` (2 VMEM ops/wave)
    auto stage = [&](int b, int t) {
        int j0t = t * BK;
        int rl = wave * 8;
        gl_lds16(&kws[base_nh + (size_t)(j0t + rl + srow8) * DH + schunk], &Ks[b][rl * DH]);
        gl_lds16(&vtws[base_vt + (size_t)(rl + srow8) * SEQ + j0t + schunk], &VTs[b][rl * BK]);
    };

    floatx4 O[4];
#pragma unroll
    for (int dt = 0; dt < 4; ++dt) O[dt] = floatx4{0.f, 0.f, 0.f, 0.f};
    floatx4 Lacc = floatx4{0.f, 0.f, 0.f, 0.f};

    // prologue: stage tile 0 into buf 0; mask for tile 0
    stage(0, 0);
    uint2 mwC = *(const uint2*)&mr0[0];
    asm volatile("s_waitcnt vmcnt(0)" ::: "memory");
    __builtin_amdgcn_s_barrier();

    // one tile iteration. cb is ALWAYS a literal at call sites -> constant-
    // folded after inlining (static LDS bases). 1-ahead staging into cb^1;
    // syncmode: 0 = vmcnt(0)+barrier (certifies tile it+1), 2 = none (last).
    auto body = [&](int it, int cb, bool do_stage, int syncmode) {
        uint2 nA = {0, 0};
        if (do_stage) {
            stage(cb ^ 1, it + 1);
            nA = *(const uint2*)&mr0[(it + 1) * 2];
        }

        // ---- K·Q^T on buffer cb ----
        bf16x8 bfK[4][2];
#pragma unroll
        for (int nt = 0; nt < 4; ++nt)
#pragma unroll
            for (int ks = 0; ks < 2; ++ks)
                bfK[nt][ks] = *(const bf16x8*)&Ks[cb][nt * 16 * DH + koff[ks]];

        float St[4][4];
        __builtin_amdgcn_s_setprio(1);
#pragma unroll
        for (int nt = 0; nt < 4; ++nt) {
            floatx4 c = {0.f, 0.f, 0.f, 0.f};
            c = __builtin_amdgcn_mfma_f32_16x16x32_bf16(bfK[nt][0], af[0], c, 0, 0, 0);
            c = __builtin_amdgcn_mfma_f32_16x16x32_bf16(bfK[nt][1], af[1], c, 0, 0, 0);
            St[nt][0] = c[0]; St[nt][1] = c[1]; St[nt][2] = c[2]; St[nt][3] = c[3];
        }
        __builtin_amdgcn_s_setprio(0);

        // ---- p = bit ? 0 : exp2(s), RNE bf16 pack, b64 store ----
#pragma unroll
        for (int nt = 0; nt < 4; ++nt) {
            unsigned w = (nt & 2) ? mwC.y : mwC.x;
            int bb = (nt & 1) * 16 + quad * 4;
            float p[4];
#pragma unroll
            for (int r = 0; r < 4; ++r) {
                float e = __builtin_amdgcn_exp2f(St[nt][r]);
                p[r] = ((w >> (bb + r)) & 1u) ? 0.f : e;
            }
            bf16x2 e01, e23;
            e01[0] = (__bf16)p[0]; e01[1] = (__bf16)p[1];
            e23[0] = (__bf16)p[2]; e23[1] = (__bf16)p[3];
            uint2 pk;
            pk.x = *(unsigned*)&e01;
            pk.y = *(unsigned*)&e23;
            *(uint2*)&Ps[wave][l16 * PAD + nt * 16 + quad * 4] = pk;
        }

        // ---- PV + row-sum MFMA ----
        bf16x8 pa[2], vb[4][2];
#pragma unroll
        for (int ks = 0; ks < 2; ++ks)
            pa[ks] = *(const bf16x8*)&Ps[wave][l16 * PAD + ks * 32 + quad * 8];
#pragma unroll
        for (int dt = 0; dt < 4; ++dt)
#pragma unroll
            for (int ks = 0; ks < 2; ++ks)
                vb[dt][ks] = *(const bf16x8*)&VTs[cb][dt * 16 * BK + voff[ks]];

        __builtin_amdgcn_s_setprio(1);
        Lacc = __builtin_amdgcn_mfma_f32_16x16x32_bf16(pa[0], vones, Lacc, 0, 0, 0);
        Lacc = __builtin_amdgcn_mfma_f32_16x16x32_bf16(pa[1], vones, Lacc, 0, 0, 0);
#pragma unroll
        for (int dt = 0; dt < 4; ++dt) {
            O[dt] = __builtin_amdgcn_mfma_f32_16x16x32_bf16(pa[0], vb[dt][0], O[dt], 0, 0, 0);
            O[dt] = __builtin_amdgcn_mfma_f32_16x16x32_bf16(pa[1], vb[dt][1], O[dt], 0, 0, 0);
        }
        __builtin_amdgcn_s_setprio(0);

        if (syncmode == 0) {
            asm volatile("s_waitcnt vmcnt(0)" ::: "memory");
            __builtin_amdgcn_s_barrier();
        }
        mwC = nA;
    };

    // 32 iterations, buffer parity cb = it & 1 (static at each call site).
    // Iter `it` stages tile it+1 into cb^1; barrier certifies it for it+1.
    for (int t2 = 0; t2 < 30; t2 += 2) {
        body(t2 + 0, 0, true, 0);
        body(t2 + 1, 1, true, 0);
    }
    body(30, 0, true, 0);    // stages tile 31 into buf 1; drain + barrier
    body(31, 1, false, 2);   // last tile, no stage, no sync

    // epilogue: Lacc holds full row-sums in (quad*4+r) layout
#pragma unroll
    for (int r = 0; r < 4; ++r) {
        float lr = Lacc[r];
        float inv = (lr > 0.f) ? 1.f / lr : 0.f;
        int row = q0 + wave * 16 + quad * 4 + r;
#pragma unroll
        for (int dt = 0; dt < 4; ++dt) {
            int col = h * DH + dt * 16 + l16;
            yws[((size_t)n * SEQ + row) * DMODEL + col] = f2bf(O[dt][r] * inv);
        }
    }
}

extern "C" void kernel_launch(void* const* d_in, const int* in_sizes, int n_in,
                              void* d_out, int out_size, void* d_ws, size_t ws_size,
                              hipStream_t stream) {
    const void* query = d_in[0];
    const void* key_  = d_in[1];
    const void* value = d_in[2];
    const void* mask  = d_in[3];
    const void* Wq = d_in[4];
    const void* bq = d_in[5];
    const void* Wk = d_in[6];
    const void* bk = d_in[7];
    const void* Wv = d_in[8];
    const void* bv = d_in[9];
    const void* Wp = d_in[10];
    const void* bp = d_in[11];

    const size_t per = (size_t)NB * NH * SEQ * DH;  // 4,194,304
    unsigned short* us = (unsigned short*)d_ws;
    unsigned short* qws  = us;
    unsigned short* kws  = us + per;
    unsigned short* vtws = us + 2 * per;
    unsigned short* abf0 = us + 3 * per;   // bf16 query acts; reused as yws after proj
    unsigned short* abf1 = us + 4 * per;
    unsigned short* abf2 = us + 5 * per;
    unsigned short* wt0  = us + 6 * per;
    unsigned short* wt1  = wt0 + 1048576;
    unsigned short* wt2  = wt1 + 1048576;
    unsigned short* wt3  = wt2 + 1048576;
    unsigned int* mbits  = (unsigned int*)(wt3 + 1048576);  // 262144 words
    unsigned short* yws = abf0;

    prep<<<dim3(14336), 256, 0, stream>>>(query, key_, value, mask,
                                          Wq, Wk, Wv, Wp,
                                          abf0, abf1, abf2,
                                          wt0, wt1, wt2, wt3, mbits);
    gemm_mfma<<<dim3(8, 32, 3), 256, 0, stream>>>(abf0, abf1, abf2, wt0, wt1, wt2,
                                                  bq, bk, bv, qws, kws, vtws, 0);
    attn_mfma<<<dim3(SEQ / BQ, NH, NB), 512, 0, stream>>>(qws, kws, vtws, mbits, yws);
    gemm_mfma<<<dim3(8, 32, 1), 256, 0, stream>>>(yws, yws, yws, wt3, wt3, wt3,
                                                  bp, bp, bp, d_out, d_out, d_out, 3);
}

// Round 14
// 275.593 us; speedup vs baseline: 1.5360x; 1.0077x over previous
//
#include <hip/hip_runtime.h>
#include <hip/hip_bf16.h>
#include <stdint.h>

typedef __attribute__((ext_vector_type(8))) __bf16 bf16x8;
typedef __attribute__((ext_vector_type(2))) __bf16 bf16x2;
typedef __attribute__((ext_vector_type(4))) float floatx4;

#define NB 2
#define SEQ 2048
#define DIN 1024
#define NH 16
#define DH 64
#define DMODEL 1024  // NH*DH
#define BQ 128
#define BK 64
#define PAD 72       // Ps LDS row stride (144 B, 16B-aligned)
#define QSCALE 0.18033688011112042f  // log2(e)/8: folds 1/sqrt(64) and ln2->exp2

__device__ __forceinline__ float bf2f(unsigned short u) {
    return __uint_as_float(((unsigned)u) << 16);
}
__device__ __forceinline__ unsigned short f2bf(float f) {
    unsigned u = __float_as_uint(f);
    unsigned r = (u + 0x7FFFu + ((u >> 16) & 1u)) >> 16;  // RNE
    return (unsigned short)r;
}
__device__ __forceinline__ float ldin(const void* p, size_t idx, int isbf) {
    return isbf ? bf2f(((const unsigned short*)p)[idx]) : ((const float*)p)[idx];
}

// global -> LDS direct DMA, 16 B/lane. LDS dest is wave-uniform base + lane*16.
__device__ __forceinline__ void gl_lds16(const void* g, void* l) {
    __builtin_amdgcn_global_load_lds(
        reinterpret_cast<__attribute__((address_space(1))) unsigned int*>(
            reinterpret_cast<uintptr_t>(g)),
        reinterpret_cast<__attribute__((address_space(3))) unsigned int*>(
            reinterpret_cast<uintptr_t>(l)),
        16, 0, 0);
}

// Per-wave dtype probes (r3/r6-proven, deterministic on pristine inputs)
__device__ __forceinline__ int wave_is_bf16(const void* p) {
    unsigned short u = ((const unsigned short*)p)[2 * (threadIdx.x & 63)];
    int e = (u >> 7) & 0xFF;
    int sane = (u == 0 || (e > 100 && e < 140)) ? 1 : 0;
    return __popcll(__ballot(sane)) >= 32;
}
__device__ __forceinline__ int wave_mask_is_int(const void* p) {
    int v = ((const int*)p)[threadIdx.x & 63];
    int zo = (v == 0 || v == 1) ? 1 : 0;
    return __popcll(__ballot(zo)) >= 48;
}

// ---------------------------------------------------------------------------
// prep: conv_a (acts->bf16) [0,12288) + mask_pack [12288,13312) +
// tiled conv_w (weights->bf16 transposed, coalesced via LDS) [13312,14336)
// r18: weight-section loads vectorized (4x float4 / 4x ushort4+cvt).
// ---------------------------------------------------------------------------
__global__ __launch_bounds__(256) void prep(
    const void* __restrict__ q, const void* __restrict__ k, const void* __restrict__ v,
    const void* __restrict__ mask,
    const void* __restrict__ wq, const void* __restrict__ wk,
    const void* __restrict__ wv, const void* __restrict__ wp,
    unsigned short* __restrict__ a0, unsigned short* __restrict__ a1,
    unsigned short* __restrict__ a2,
    unsigned short* __restrict__ t0, unsigned short* __restrict__ t1,
    unsigned short* __restrict__ t2, unsigned short* __restrict__ t3,
    unsigned int* __restrict__ mbits)
{
    __shared__ __align__(16) float xls[64][68];
    const int b = blockIdx.x;
    const int tid = threadIdx.x;
    if (b < 12288) {
        int z = b >> 12, blk = b & 4095;
        const void* src = (z == 0) ? q : (z == 1) ? k : v;
        unsigned short* dst = (z == 0) ? a0 : (z == 1) ? a1 : a2;
        int isbf = wave_is_bf16(src);
        size_t i = ((size_t)blk * 256 + tid) * 4;
        if (isbf) {
            *(ushort4*)&dst[i] = *(const ushort4*)((const unsigned short*)src + i);
        } else {
            float4 f = *(const float4*)((const float*)src + i);
            ushort4 o;
            o.x = f2bf(f.x); o.y = f2bf(f.y); o.z = f2bf(f.z); o.w = f2bf(f.w);
            *(ushort4*)&dst[i] = o;
        }
    } else if (b < 13312) {
        int blk = b - 12288;
        int w = blk * 256 + tid;
        int is_int = wave_mask_is_int(mask);
        unsigned bits = 0;
        if (is_int) {
            const int4* p = (const int4*)mask + (size_t)w * 8;
#pragma unroll
            for (int g = 0; g < 8; ++g) {
                int4 vv = p[g];
                bits |= (unsigned)(vv.x != 0) << (g * 4 + 0);
                bits |= (unsigned)(vv.y != 0) << (g * 4 + 1);
                bits |= (unsigned)(vv.z != 0) << (g * 4 + 2);
                bits |= (unsigned)(vv.w != 0) << (g * 4 + 3);
            }
        } else {
            const uint4* p = (const uint4*)mask + (size_t)w * 2;
#pragma unroll
            for (int g = 0; g < 2; ++g) {
                uint4 vv = p[g];
                unsigned ws4[4] = {vv.x, vv.y, vv.z, vv.w};
#pragma unroll
                for (int c = 0; c < 4; ++c)
#pragma unroll
                    for (int bb = 0; bb < 4; ++bb)
                        bits |= (unsigned)(((ws4[c] >> (8 * bb)) & 0xFFu) != 0)
                                << (g * 16 + c * 4 + bb);
            }
        }
        mbits[w] = bits;
    } else {
        int zb = b - 13312;
        int z = zb >> 8, t = zb & 255;
        const void* src = (z == 0) ? wq : (z == 1) ? wk : (z == 2) ? wv : wp;
        unsigned short* dst = (z == 0) ? t0 : (z == 1) ? t1 : (z == 2) ? t2 : t3;
        int isbf = wave_is_bf16(src);
        int r = tid >> 2, cs = (tid & 3) * 16;

        // vectorized 16-elem row load into xls[r][cs..cs+15] (16B-aligned)
        size_t idx0;
        if (z < 3) {
            int hh = t >> 4, m0 = (t & 15) * 64;
            idx0 = (size_t)hh * 65536 + (size_t)(m0 + r) * 64 + cs;
        } else {
            int m0 = (t >> 4) * 64, c0 = (t & 15) * 64;
            idx0 = (size_t)(m0 + r) * 1024 + c0 + cs;
        }
        float4* xrow = (float4*)&xls[r][cs];
        if (isbf) {
            const unsigned short* sp = (const unsigned short*)src + idx0;
#pragma unroll
            for (int g = 0; g < 4; ++g) {
                ushort4 u = *(const ushort4*)(sp + g * 4);
                float4 f;
                f.x = bf2f(u.x); f.y = bf2f(u.y); f.z = bf2f(u.z); f.w = bf2f(u.w);
                xrow[g] = f;
            }
        } else {
            const float4* fp = (const float4*)((const float*)src + idx0);
#pragma unroll
            for (int g = 0; g < 4; ++g) xrow[g] = fp[g];
        }
        __syncthreads();

        int d2 = tid >> 2, ms = (tid & 3) * 16;
        size_t orow;
        if (z < 3) {
            int hh = t >> 4, m0 = (t & 15) * 64;
            orow = (size_t)(hh * 64 + d2) * 1024 + m0 + ms;
        } else {
            int m0 = (t >> 4) * 64, c0 = (t & 15) * 64;
            orow = (size_t)(c0 + d2) * 1024 + m0 + ms;
        }
#pragma unroll
        for (int g = 0; g < 4; ++g) {
            ushort4 o;
            o.x = f2bf(xls[ms + g * 4 + 0][d2]);
            o.y = f2bf(xls[ms + g * 4 + 1][d2]);
            o.z = f2bf(xls[ms + g * 4 + 2][d2]);
            o.w = f2bf(xls[ms + g * 4 + 3][d2]);
            *(ushort4*)&dst[orow + g * 4] = o;
        }
    }
}

// ---------------------------------------------------------------------------
// Unified MFMA GEMM with global_load_lds staging (r9). mode: 0 Q (prescaled
// QSCALE)->(n,h,k,d); 1 K; 2 V->(n,h,d,k) LDS-transposed; 3 OUT.
// r17: XCD-aware tile swizzle (T1), bijective within each 256-block z-slice.
// r20: modes 0/1 epilogue vectorized via the mode-2 LDS-restage pattern —
// 64 scalar 2B stores/thread -> 8 contiguous bf16x8 (16B) stores (8-col
// chunks never cross a head boundary since 8 | 64). Same smem buffer
// ([128][136] shorts = 17408), post-k-loop-barrier safe.
// ---------------------------------------------------------------------------
__global__ __launch_bounds__(256) void gemm_mfma(
    const unsigned short* __restrict__ A0, const unsigned short* __restrict__ A1,
    const unsigned short* __restrict__ A2,
    const unsigned short* __restrict__ B0, const unsigned short* __restrict__ B1,
    const unsigned short* __restrict__ B2,
    const void* __restrict__ bias0, const void* __restrict__ bias1,
    const void* __restrict__ bias2,
    void* __restrict__ C0, void* __restrict__ C1, void* __restrict__ C2,
    int mode0)
{
    const int z = blockIdx.z;
    const unsigned short* A  = (z == 0) ? A0 : (z == 1) ? A1 : A2;
    const unsigned short* BT = (z == 0) ? B0 : (z == 1) ? B1 : B2;
    const void* bias = (z == 0) ? bias0 : (z == 1) ? bias1 : bias2;
    void* C = (z == 0) ? C0 : (z == 1) ? C1 : C2;
    const int mode = mode0 + z;
    const int isbf = wave_is_bf16(bias);
    const float scl = (mode == 0) ? QSCALE : 1.0f;

    const int lin  = blockIdx.x + (blockIdx.y << 3);   // 0..255
    const int xcd8 = lin & 7, loc = lin >> 3;          // loc 0..31
    const int n0   = (loc & 7) * 128;
    const int m0g  = ((xcd8 << 2) + (loc >> 3)) * 128;

    const int tid = threadIdx.x;
    const int wave = tid >> 6, lane = tid & 63;
    const int l16 = lane & 15, quad = lane >> 4;
    const int wm = wave & 1, wn = wave >> 1;

    __shared__ __align__(16) unsigned short smem[17408];
    unsigned short* As = smem;
    unsigned short* Bs = smem + 8192;

    floatx4 acc[4][4];
#pragma unroll
    for (int mt = 0; mt < 4; ++mt)
#pragma unroll
        for (int nt = 0; nt < 4; ++nt) acc[mt][nt] = floatx4{0.f, 0.f, 0.f, 0.f};

    const int lrow8 = lane >> 3;
    const int lseg  = (lane & 7) * 8;

    for (int kk = 0; kk < 1024; kk += 64) {
#pragma unroll
        for (int j = 0; j < 4; ++j) {
            int row0 = wave * 8 + j * 32;
            gl_lds16(&A[(size_t)(m0g + row0 + lrow8) * 1024 + kk + lseg], &As[row0 * 64]);
            gl_lds16(&BT[(size_t)(n0 + row0 + lrow8) * 1024 + kk + lseg], &Bs[row0 * 64]);
        }
        __syncthreads();
#pragma unroll
        for (int ks = 0; ks < 2; ++ks) {
            bf16x8 af[4], bf[4];
#pragma unroll
            for (int mt = 0; mt < 4; ++mt)
                af[mt] = *(const bf16x8*)&As[(wm * 64 + mt * 16 + l16) * 64 + ks * 32 + quad * 8];
#pragma unroll
            for (int nt = 0; nt < 4; ++nt)
                bf[nt] = *(const bf16x8*)&Bs[(wn * 64 + nt * 16 + l16) * 64 + ks * 32 + quad * 8];
#pragma unroll
            for (int mt = 0; mt < 4; ++mt)
#pragma unroll
                for (int nt = 0; nt < 4; ++nt)
                    acc[mt][nt] = __builtin_amdgcn_mfma_f32_16x16x32_bf16(af[mt], bf[nt], acc[mt][nt], 0, 0, 0);
        }
        __syncthreads();
    }

    float bv4[4];
#pragma unroll
    for (int nt = 0; nt < 4; ++nt)
        bv4[nt] = ldin(bias, n0 + wn * 64 + nt * 16 + l16, isbf);

    if (mode <= 1) {  // Q/K -> (n,h,k,d), vectorized via LDS restage (r20)
#pragma unroll
        for (int mt = 0; mt < 4; ++mt)
#pragma unroll
            for (int nt = 0; nt < 4; ++nt)
#pragma unroll
                for (int reg = 0; reg < 4; ++reg) {
                    int m_l = wm * 64 + mt * 16 + quad * 4 + reg;
                    int c_l = wn * 64 + nt * 16 + l16;
                    smem[m_l * 136 + c_l] = f2bf((acc[mt][nt][reg] + bv4[nt]) * scl);
                }
        __syncthreads();
        unsigned short* O = (unsigned short*)C;
#pragma unroll
        for (int j = 0; j < 8; ++j) {
            int i = tid + j * 256;           // 0..2047
            int m_l = i >> 4;                // 128 rows
            int c8 = (i & 15) * 8;           // 8-aligned col start (within one head)
            int row = m0g + m_l;
            int nb = row >> 11, kq = row & (SEQ - 1);
            int cg = n0 + c8, hh = cg >> 6, d = cg & 63;
            *(bf16x8*)&O[(((size_t)nb * NH + hh) * SEQ + kq) * DH + d] =
                *(const bf16x8*)&smem[m_l * 136 + c8];
        }
    } else if (mode == 2) {  // V -> (n,h,d,k) via LDS transpose
#pragma unroll
        for (int mt = 0; mt < 4; ++mt)
#pragma unroll
            for (int nt = 0; nt < 4; ++nt)
#pragma unroll
                for (int reg = 0; reg < 4; ++reg) {
                    int m_l = wm * 64 + mt * 16 + quad * 4 + reg;
                    int c_l = wn * 64 + nt * 16 + l16;
                    smem[c_l * 136 + m_l] = f2bf(acc[mt][nt][reg] + bv4[nt]);
                }
        __syncthreads();
        unsigned short* O = (unsigned short*)C;
        int nb = m0g >> 11;
        int kq0 = m0g & (SEQ - 1);
#pragma unroll
        for (int j = 0; j < 8; ++j) {
            int i = tid + j * 256;
            int c_l = i >> 4, m8 = (i & 15) * 8;
            int cg = n0 + c_l, h = cg >> 6, d = cg & 63;
            *(bf16x8*)&O[(((size_t)nb * NH + h) * DH + d) * SEQ + kq0 + m8] =
                *(const bf16x8*)&smem[c_l * 136 + m8];
        }
    } else {  // OUT row-major, dual dtype
        unsigned short* Ob = (unsigned short*)C;
        float* Of = (float*)C;
#pragma unroll
        for (int mt = 0; mt < 4; ++mt)
#pragma unroll
            for (int reg = 0; reg < 4; ++reg) {
                int row = m0g + wm * 64 + mt * 16 + quad * 4 + reg;
#pragma unroll
                for (int nt = 0; nt < 4; ++nt) {
                    int c = n0 + wn * 64 + nt * 16 + l16;
                    float v = acc[mt][nt][reg] + bv4[nt];
                    if (isbf) Ob[(size_t)row * DMODEL + c] = f2bf(v);
                    else      Of[(size_t)row * DMODEL + c] = v;
                }
            }
    }
}

// ---------------------------------------------------------------------------
// MFMA flash attention — r17 RESTORED verbatim (proven 60.0 us). r19's dbuf
// was 61.3 us: occupancy did NOT rise (33% both) and the per-iter vmcnt(0)
// drain cost ~1.3 us vs r17's counted vmcnt(3). Triple buffer, DMA two tiles
// ahead, unroll-by-3 static buffer indices, setprio, XCD swizzle,
// ones-MFMA row-sum, launch_bounds(512,4).
// ---------------------------------------------------------------------------
__global__ __launch_bounds__(512, 4) void attn_mfma(
    const unsigned short* __restrict__ qws, const unsigned short* __restrict__ kws,
    const unsigned short* __restrict__ vtws, const unsigned int* __restrict__ mbits,
    unsigned short* __restrict__ yws)
{
    // XCD-aware remap (r13-proven): 64 blocks/XCD = 4 (n,h) x 16 qt.
    const int linear = blockIdx.x + (blockIdx.y << 4) + (blockIdx.z << 8);
    const int xcd = linear & 7, loc = linear >> 3;
    const int hn  = (xcd << 2) + (loc >> 4);   // 0..31
    const int qt  = loc & 15;
    const int h   = hn & 15;
    const int n   = hn >> 4;

    const int tid  = threadIdx.x;
    const int wave = tid >> 6;          // 0..7
    const int lane = tid & 63;
    const int l16  = lane & 15;
    const int quad = lane >> 4;

    __shared__ __align__(16) unsigned short Ks[3][BK * DH];    // [key][d], swizzled
    __shared__ __align__(16) unsigned short VTs[3][DH * BK];   // [d][key], swizzled
    __shared__ __align__(16) unsigned short Ps[8][16 * PAD];   // per-wave [qrow][key]

    const size_t base_nh = ((size_t)n * NH + h) * SEQ * DH;
    const size_t base_vt = ((size_t)n * NH + h) * DH * SEQ;
    const int q0 = qt * BQ;
    const int qrow = wave * 16 + l16;   // this lane's q-row within the block

    // mask-bit row pointer + Q fragments (prescaled QSCALE)
    const unsigned int* mr0 = mbits + ((size_t)n * SEQ + q0 + qrow) * (SEQ / 32);
    bf16x8 af[2];
    {
        const unsigned short* qp = qws + base_nh + (size_t)(q0 + qrow) * DH + quad * 8;
        af[0] = *(const bf16x8*)qp;
        af[1] = *(const bf16x8*)(qp + 32);
    }

    // DMA staging geometry + XOR swizzle (r9-proven). Each wave stages 8 rows
    // of K and 8 rows of V^T per tile (8 waves x 8 = 64 rows each).
    const int srow8  = lane >> 3;
    const int schunk = ((lane & 7) ^ srow8) * 8;
    const int swz = l16 & 7;
    int koff[2], voff[2];
#pragma unroll
    for (int ks = 0; ks < 2; ++ks) {
        koff[ks] = l16 * DH + (((ks * 4 + quad) ^ swz) * 8);
        voff[ks] = l16 * BK + (((ks * 4 + quad) ^ swz) * 8);
    }

    // ones B-fragment for the row-sum MFMA
    bf16x8 vones;
#pragma unroll
    for (int j = 0; j < 8; ++j) vones[j] = (__bf16)1.0f;

    // stage tile `t` into buffer slot `b` (2 VMEM ops/wave)
    auto stage = [&](int b, int t) {
        int j0t = t * BK;
        int rl = wave * 8;
        gl_lds16(&kws[base_nh + (size_t)(j0t + rl + srow8) * DH + schunk], &Ks[b][rl * DH]);
        gl_lds16(&vtws[base_vt + (size_t)(rl + srow8) * SEQ + j0t + schunk], &VTs[b][rl * BK]);
    };

    floatx4 O[4];
#pragma unroll
    for (int dt = 0; dt < 4; ++dt) O[dt] = floatx4{0.f, 0.f, 0.f, 0.f};
    floatx4 Lacc = floatx4{0.f, 0.f, 0.f, 0.f};

    // prologue: stage tiles 0 and 1; masks for tiles 0 (cur) and 1 (next)
    stage(0, 0);
    stage(1, 1);
    uint2 mwC = *(const uint2*)&mr0[0];
    uint2 mwN = *(const uint2*)&mr0[2];
    // one-time full drain (order-robust), then publish
    asm volatile("s_waitcnt vmcnt(0)" ::: "memory");
    __builtin_amdgcn_s_barrier();

    // one tile iteration. cb is ALWAYS a literal at call sites -> constant-
    // folded after inlining (static LDS bases). syncmode: 0 = vmcnt(3)+bar
    // (main), 1 = vmcnt(0)+bar (it=30), 2 = none (it=31).
    auto body = [&](int it, int cb, bool do_stage, int syncmode) {
        uint2 nA = {0, 0};
        if (do_stage) {
            int b2 = cb + 2; if (b2 >= 3) b2 -= 3;
            stage(b2, it + 2);
            nA = *(const uint2*)&mr0[(it + 2) * 2];
        }

        // ---- K·Q^T on buffer cb ----
        bf16x8 bfK[4][2];
#pragma unroll
        for (int nt = 0; nt < 4; ++nt)
#pragma unroll
            for (int ks = 0; ks < 2; ++ks)
                bfK[nt][ks] = *(const bf16x8*)&Ks[cb][nt * 16 * DH + koff[ks]];

        float St[4][4];
        __builtin_amdgcn_s_setprio(1);
#pragma unroll
        for (int nt = 0; nt < 4; ++nt) {
            floatx4 c = {0.f, 0.f, 0.f, 0.f};
            c = __builtin_amdgcn_mfma_f32_16x16x32_bf16(bfK[nt][0], af[0], c, 0, 0, 0);
            c = __builtin_amdgcn_mfma_f32_16x16x32_bf16(bfK[nt][1], af[1], c, 0, 0, 0);
            St[nt][0] = c[0]; St[nt][1] = c[1]; St[nt][2] = c[2]; St[nt][3] = c[3];
        }
        __builtin_amdgcn_s_setprio(0);

        // ---- p = bit ? 0 : exp2(s), RNE bf16 pack, b64 store ----
#pragma unroll
        for (int nt = 0; nt < 4; ++nt) {
            unsigned w = (nt & 2) ? mwC.y : mwC.x;
            int bb = (nt & 1) * 16 + quad * 4;
            float p[4];
#pragma unroll
            for (int r = 0; r < 4; ++r) {
                float e = __builtin_amdgcn_exp2f(St[nt][r]);
                p[r] = ((w >> (bb + r)) & 1u) ? 0.f : e;
            }
            bf16x2 e01, e23;
            e01[0] = (__bf16)p[0]; e01[1] = (__bf16)p[1];
            e23[0] = (__bf16)p[2]; e23[1] = (__bf16)p[3];
            uint2 pk;
            pk.x = *(unsigned*)&e01;
            pk.y = *(unsigned*)&e23;
            *(uint2*)&Ps[wave][l16 * PAD + nt * 16 + quad * 4] = pk;
        }

        // ---- PV + row-sum MFMA ----
        bf16x8 pa[2], vb[4][2];
#pragma unroll
        for (int ks = 0; ks < 2; ++ks)
            pa[ks] = *(const bf16x8*)&Ps[wave][l16 * PAD + ks * 32 + quad * 8];
#pragma unroll
        for (int dt = 0; dt < 4; ++dt)
#pragma unroll
            for (int ks = 0; ks < 2; ++ks)
                vb[dt][ks] = *(const bf16x8*)&VTs[cb][dt * 16 * BK + voff[ks]];

        __builtin_amdgcn_s_setprio(1);
        Lacc = __builtin_amdgcn_mfma_f32_16x16x32_bf16(pa[0], vones, Lacc, 0, 0, 0);
        Lacc = __builtin_amdgcn_mfma_f32_16x16x32_bf16(pa[1], vones, Lacc, 0, 0, 0);
#pragma unroll
        for (int dt = 0; dt < 4; ++dt) {
            O[dt] = __builtin_amdgcn_mfma_f32_16x16x32_bf16(pa[0], vb[dt][0], O[dt], 0, 0, 0);
            O[dt] = __builtin_amdgcn_mfma_f32_16x16x32_bf16(pa[1], vb[dt][1], O[dt], 0, 0, 0);
        }
        __builtin_amdgcn_s_setprio(0);

        if (syncmode == 0) {
            asm volatile("s_waitcnt vmcnt(3)" ::: "memory");
            __builtin_amdgcn_s_barrier();
        } else if (syncmode == 1) {
            asm volatile("s_waitcnt vmcnt(0)" ::: "memory");
            __builtin_amdgcn_s_barrier();
        }
        mwC = mwN;
        mwN = nA;
    };

    // main: 30 uniform iterations as 10 triples with static buffer index.
    // buffer sequence cb = it % 3; tile it+2 staged into (cb+2)%3, consumed
    // two iterations later at cb' = (it+2)%3 — invariant preserved.
    for (int t3 = 0; t3 < 30; t3 += 3) {
        body(t3 + 0, 0, true, 0);
        body(t3 + 1, 1, true, 0);
        body(t3 + 2, 2, true, 0);
    }
    body(30, 0, false, 1);   // consumes buf 0 (staged at it=28); full drain
    body(31, 1, false, 2);   // last tile, no sync needed

    // epilogue: Lacc holds full row-sums in (quad*4+r) layout
#pragma unroll
    for (int r = 0; r < 4; ++r) {
        float lr = Lacc[r];
        float inv = (lr > 0.f) ? 1.f / lr : 0.f;
        int row = q0 + wave * 16 + quad * 4 + r;
#pragma unroll
        for (int dt = 0; dt < 4; ++dt) {
            int col = h * DH + dt * 16 + l16;
            yws[((size_t)n * SEQ + row) * DMODEL + col] = f2bf(O[dt][r] * inv);
        }
    }
}

extern "C" void kernel_launch(void* const* d_in, const int* in_sizes, int n_in,
                              void* d_out, int out_size, void* d_ws, size_t ws_size,
                              hipStream_t stream) {
    const void* query = d_in[0];
    const void* key_  = d_in[1];
    const void* value = d_in[2];
    const void* mask  = d_in[3];
    const void* Wq = d_in[4];
    const void* bq = d_in[5];
    const void* Wk = d_in[6];
    const void* bk = d_in[7];
    const void* Wv = d_in[8];
    const void* bv = d_in[9];
    const void* Wp = d_in[10];
    const void* bp = d_in[11];

    const size_t per = (size_t)NB * NH * SEQ * DH;  // 4,194,304
    unsigned short* us = (unsigned short*)d_ws;
    unsigned short* qws  = us;
    unsigned short* kws  = us + per;
    unsigned short* vtws = us + 2 * per;
    unsigned short* abf0 = us + 3 * per;   // bf16 query acts; reused as yws after proj
    unsigned short* abf1 = us + 4 * per;
    unsigned short* abf2 = us + 5 * per;
    unsigned short* wt0  = us + 6 * per;
    unsigned short* wt1  = wt0 + 1048576;
    unsigned short* wt2  = wt1 + 1048576;
    unsigned short* wt3  = wt2 + 1048576;
    unsigned int* mbits  = (unsigned int*)(wt3 + 1048576);  // 262144 words
    unsigned short* yws = abf0;

    prep<<<dim3(14336), 256, 0, stream>>>(query, key_, value, mask,
                                          Wq, Wk, Wv, Wp,
                                          abf0, abf1, abf2,
                                          wt0, wt1, wt2, wt3, mbits);
    gemm_mfma<<<dim3(8, 32, 3), 256, 0, stream>>>(abf0, abf1, abf2, wt0, wt1, wt2,
                                                  bq, bk, bv, qws, kws, vtws, 0);
    attn_mfma<<<dim3(SEQ / BQ, NH, NB), 512, 0, stream>>>(qws, kws, vtws, mbits, yws);
    gemm_mfma<<<dim3(8, 32, 1), 256, 0, stream>>>(yws, yws, yws, wt3, wt3, wt3,
                                                  bp, bp, bp, d_out, d_out, d_out, 3);
}

// Round 16
// 264.494 us; speedup vs baseline: 1.6005x; 1.0420x over previous
//
#include <hip/hip_runtime.h>
#include <hip/hip_bf16.h>
#include <stdint.h>

typedef __attribute__((ext_vector_type(8))) __bf16 bf16x8;
typedef __attribute__((ext_vector_type(2))) __bf16 bf16x2;
typedef __attribute__((ext_vector_type(4))) float floatx4;

#define NB 2
#define SEQ 2048
#define DIN 1024
#define NH 16
#define DH 64
#define DMODEL 1024  // NH*DH
#define BQ 128
#define BK 64
#define PAD 72       // Ps LDS row stride (144 B, 16B-aligned)
#define QSCALE 0.18033688011112042f  // log2(e)/8: folds 1/sqrt(64) and ln2->exp2

__device__ __forceinline__ float bf2f(unsigned short u) {
    return __uint_as_float(((unsigned)u) << 16);
}
__device__ __forceinline__ unsigned short f2bf(float f) {
    unsigned u = __float_as_uint(f);
    unsigned r = (u + 0x7FFFu + ((u >> 16) & 1u)) >> 16;  // RNE
    return (unsigned short)r;
}
__device__ __forceinline__ float ldin(const void* p, size_t idx, int isbf) {
    return isbf ? bf2f(((const unsigned short*)p)[idx]) : ((const float*)p)[idx];
}

// global -> LDS direct DMA, 16 B/lane. LDS dest is wave-uniform base + lane*16.
__device__ __forceinline__ void gl_lds16(const void* g, void* l) {
    __builtin_amdgcn_global_load_lds(
        reinterpret_cast<__attribute__((address_space(1))) unsigned int*>(
            reinterpret_cast<uintptr_t>(g)),
        reinterpret_cast<__attribute__((address_space(3))) unsigned int*>(
            reinterpret_cast<uintptr_t>(l)),
        16, 0, 0);
}

// Per-wave dtype probes (r3/r6-proven, deterministic on pristine inputs)
__device__ __forceinline__ int wave_is_bf16(const void* p) {
    unsigned short u = ((const unsigned short*)p)[2 * (threadIdx.x & 63)];
    int e = (u >> 7) & 0xFF;
    int sane = (u == 0 || (e > 100 && e < 140)) ? 1 : 0;
    return __popcll(__ballot(sane)) >= 32;
}
__device__ __forceinline__ int wave_mask_is_int(const void* p) {
    int v = ((const int*)p)[threadIdx.x & 63];
    int zo = (v == 0 || v == 1) ? 1 : 0;
    return __popcll(__ballot(zo)) >= 48;
}

// ---------------------------------------------------------------------------
// prep: conv_a (acts->bf16) [0,12288) + mask_pack [12288,13312) +
// tiled conv_w (weights->bf16 transposed, coalesced via LDS) [13312,14336)
// r18: weight-section loads vectorized (4x float4 / 4x ushort4+cvt).
// ---------------------------------------------------------------------------
__global__ __launch_bounds__(256) void prep(
    const void* __restrict__ q, const void* __restrict__ k, const void* __restrict__ v,
    const void* __restrict__ mask,
    const void* __restrict__ wq, const void* __restrict__ wk,
    const void* __restrict__ wv, const void* __restrict__ wp,
    unsigned short* __restrict__ a0, unsigned short* __restrict__ a1,
    unsigned short* __restrict__ a2,
    unsigned short* __restrict__ t0, unsigned short* __restrict__ t1,
    unsigned short* __restrict__ t2, unsigned short* __restrict__ t3,
    unsigned int* __restrict__ mbits)
{
    __shared__ __align__(16) float xls[64][68];
    const int b = blockIdx.x;
    const int tid = threadIdx.x;
    if (b < 12288) {
        int z = b >> 12, blk = b & 4095;
        const void* src = (z == 0) ? q : (z == 1) ? k : v;
        unsigned short* dst = (z == 0) ? a0 : (z == 1) ? a1 : a2;
        int isbf = wave_is_bf16(src);
        size_t i = ((size_t)blk * 256 + tid) * 4;
        if (isbf) {
            *(ushort4*)&dst[i] = *(const ushort4*)((const unsigned short*)src + i);
        } else {
            float4 f = *(const float4*)((const float*)src + i);
            ushort4 o;
            o.x = f2bf(f.x); o.y = f2bf(f.y); o.z = f2bf(f.z); o.w = f2bf(f.w);
            *(ushort4*)&dst[i] = o;
        }
    } else if (b < 13312) {
        int blk = b - 12288;
        int w = blk * 256 + tid;
        int is_int = wave_mask_is_int(mask);
        unsigned bits = 0;
        if (is_int) {
            const int4* p = (const int4*)mask + (size_t)w * 8;
#pragma unroll
            for (int g = 0; g < 8; ++g) {
                int4 vv = p[g];
                bits |= (unsigned)(vv.x != 0) << (g * 4 + 0);
                bits |= (unsigned)(vv.y != 0) << (g * 4 + 1);
                bits |= (unsigned)(vv.z != 0) << (g * 4 + 2);
                bits |= (unsigned)(vv.w != 0) << (g * 4 + 3);
            }
        } else {
            const uint4* p = (const uint4*)mask + (size_t)w * 2;
#pragma unroll
            for (int g = 0; g < 2; ++g) {
                uint4 vv = p[g];
                unsigned ws4[4] = {vv.x, vv.y, vv.z, vv.w};
#pragma unroll
                for (int c = 0; c < 4; ++c)
#pragma unroll
                    for (int bb = 0; bb < 4; ++bb)
                        bits |= (unsigned)(((ws4[c] >> (8 * bb)) & 0xFFu) != 0)
                                << (g * 16 + c * 4 + bb);
            }
        }
        mbits[w] = bits;
    } else {
        int zb = b - 13312;
        int z = zb >> 8, t = zb & 255;
        const void* src = (z == 0) ? wq : (z == 1) ? wk : (z == 2) ? wv : wp;
        unsigned short* dst = (z == 0) ? t0 : (z == 1) ? t1 : (z == 2) ? t2 : t3;
        int isbf = wave_is_bf16(src);
        int r = tid >> 2, cs = (tid & 3) * 16;

        // vectorized 16-elem row load into xls[r][cs..cs+15] (16B-aligned)
        size_t idx0;
        if (z < 3) {
            int hh = t >> 4, m0 = (t & 15) * 64;
            idx0 = (size_t)hh * 65536 + (size_t)(m0 + r) * 64 + cs;
        } else {
            int m0 = (t >> 4) * 64, c0 = (t & 15) * 64;
            idx0 = (size_t)(m0 + r) * 1024 + c0 + cs;
        }
        float4* xrow = (float4*)&xls[r][cs];
        if (isbf) {
            const unsigned short* sp = (const unsigned short*)src + idx0;
#pragma unroll
            for (int g = 0; g < 4; ++g) {
                ushort4 u = *(const ushort4*)(sp + g * 4);
                float4 f;
                f.x = bf2f(u.x); f.y = bf2f(u.y); f.z = bf2f(u.z); f.w = bf2f(u.w);
                xrow[g] = f;
            }
        } else {
            const float4* fp = (const float4*)((const float*)src + idx0);
#pragma unroll
            for (int g = 0; g < 4; ++g) xrow[g] = fp[g];
        }
        __syncthreads();

        int d2 = tid >> 2, ms = (tid & 3) * 16;
        size_t orow;
        if (z < 3) {
            int hh = t >> 4, m0 = (t & 15) * 64;
            orow = (size_t)(hh * 64 + d2) * 1024 + m0 + ms;
        } else {
            int m0 = (t >> 4) * 64, c0 = (t & 15) * 64;
            orow = (size_t)(c0 + d2) * 1024 + m0 + ms;
        }
#pragma unroll
        for (int g = 0; g < 4; ++g) {
            ushort4 o;
            o.x = f2bf(xls[ms + g * 4 + 0][d2]);
            o.y = f2bf(xls[ms + g * 4 + 1][d2]);
            o.z = f2bf(xls[ms + g * 4 + 2][d2]);
            o.w = f2bf(xls[ms + g * 4 + 3][d2]);
            *(ushort4*)&dst[orow + g * 4] = o;
        }
    }
}

// ---------------------------------------------------------------------------
// Unified MFMA GEMM with global_load_lds staging (r9). mode: 0 Q (prescaled
// QSCALE)->(n,h,k,d); 1 K; 2 V->(n,h,d,k) LDS-transposed; 3 OUT.
// r17: XCD-aware tile swizzle (T1). r20: vectorized Q/K epilogue.
// r21: LDS XOR-swizzle on As/Bs (T2) — the [row][64] layout has row stride
// 128 B = 32 banks, so fragment reads (row varies by l16, col fixed) were a
// 16-way bank conflict: SQ_LDS_BANK_CONFLICT 9.6M cycles/dispatch ~= 24% of
// the QKV GEMM. Fix is the r9-proven attn pattern (rule #21: swizzle BOTH
// sides): pre-swizzled GLOBAL source column ((lane&7)^(lane>>3))*8 with
// linear LDS dest, and ^swz on the fragment-read chunk ((ks*4+quad)^(l16&7)).
// row&7 == l16&7 (row = 16k + l16), so the involution matches exactly.
// ---------------------------------------------------------------------------
__global__ __launch_bounds__(256) void gemm_mfma(
    const unsigned short* __restrict__ A0, const unsigned short* __restrict__ A1,
    const unsigned short* __restrict__ A2,
    const unsigned short* __restrict__ B0, const unsigned short* __restrict__ B1,
    const unsigned short* __restrict__ B2,
    const void* __restrict__ bias0, const void* __restrict__ bias1,
    const void* __restrict__ bias2,
    void* __restrict__ C0, void* __restrict__ C1, void* __restrict__ C2,
    int mode0)
{
    const int z = blockIdx.z;
    const unsigned short* A  = (z == 0) ? A0 : (z == 1) ? A1 : A2;
    const unsigned short* BT = (z == 0) ? B0 : (z == 1) ? B1 : B2;
    const void* bias = (z == 0) ? bias0 : (z == 1) ? bias1 : bias2;
    void* C = (z == 0) ? C0 : (z == 1) ? C1 : C2;
    const int mode = mode0 + z;
    const int isbf = wave_is_bf16(bias);
    const float scl = (mode == 0) ? QSCALE : 1.0f;

    const int lin  = blockIdx.x + (blockIdx.y << 3);   // 0..255
    const int xcd8 = lin & 7, loc = lin >> 3;          // loc 0..31
    const int n0   = (loc & 7) * 128;
    const int m0g  = ((xcd8 << 2) + (loc >> 3)) * 128;

    const int tid = threadIdx.x;
    const int wave = tid >> 6, lane = tid & 63;
    const int l16 = lane & 15, quad = lane >> 4;
    const int wm = wave & 1, wn = wave >> 1;

    __shared__ __align__(16) unsigned short smem[17408];
    unsigned short* As = smem;
    unsigned short* Bs = smem + 8192;

    floatx4 acc[4][4];
#pragma unroll
    for (int mt = 0; mt < 4; ++mt)
#pragma unroll
        for (int nt = 0; nt < 4; ++nt) acc[mt][nt] = floatx4{0.f, 0.f, 0.f, 0.f};

    const int lrow8 = lane >> 3;
    const int lseg  = ((lane & 7) ^ lrow8) * 8;   // r21: pre-swizzled source col
    const int swz   = l16 & 7;                    // r21: read-side XOR

    for (int kk = 0; kk < 1024; kk += 64) {
#pragma unroll
        for (int j = 0; j < 4; ++j) {
            int row0 = wave * 8 + j * 32;
            gl_lds16(&A[(size_t)(m0g + row0 + lrow8) * 1024 + kk + lseg], &As[row0 * 64]);
            gl_lds16(&BT[(size_t)(n0 + row0 + lrow8) * 1024 + kk + lseg], &Bs[row0 * 64]);
        }
        __syncthreads();
#pragma unroll
        for (int ks = 0; ks < 2; ++ks) {
            bf16x8 af[4], bf[4];
#pragma unroll
            for (int mt = 0; mt < 4; ++mt)
                af[mt] = *(const bf16x8*)&As[(wm * 64 + mt * 16 + l16) * 64 +
                                             (((ks * 4 + quad) ^ swz) * 8)];
#pragma unroll
            for (int nt = 0; nt < 4; ++nt)
                bf[nt] = *(const bf16x8*)&Bs[(wn * 64 + nt * 16 + l16) * 64 +
                                             (((ks * 4 + quad) ^ swz) * 8)];
#pragma unroll
            for (int mt = 0; mt < 4; ++mt)
#pragma unroll
                for (int nt = 0; nt < 4; ++nt)
                    acc[mt][nt] = __builtin_amdgcn_mfma_f32_16x16x32_bf16(af[mt], bf[nt], acc[mt][nt], 0, 0, 0);
        }
        __syncthreads();
    }

    float bv4[4];
#pragma unroll
    for (int nt = 0; nt < 4; ++nt)
        bv4[nt] = ldin(bias, n0 + wn * 64 + nt * 16 + l16, isbf);

    if (mode <= 1) {  // Q/K -> (n,h,k,d), vectorized via LDS restage (r20)
#pragma unroll
        for (int mt = 0; mt < 4; ++mt)
#pragma unroll
            for (int nt = 0; nt < 4; ++nt)
#pragma unroll
                for (int reg = 0; reg < 4; ++reg) {
                    int m_l = wm * 64 + mt * 16 + quad * 4 + reg;
                    int c_l = wn * 64 + nt * 16 + l16;
                    smem[m_l * 136 + c_l] = f2bf((acc[mt][nt][reg] + bv4[nt]) * scl);
                }
        __syncthreads();
        unsigned short* O = (unsigned short*)C;
#pragma unroll
        for (int j = 0; j < 8; ++j) {
            int i = tid + j * 256;           // 0..2047
            int m_l = i >> 4;                // 128 rows
            int c8 = (i & 15) * 8;           // 8-aligned col start (within one head)
            int row = m0g + m_l;
            int nb = row >> 11, kq = row & (SEQ - 1);
            int cg = n0 + c8, hh = cg >> 6, d = cg & 63;
            *(bf16x8*)&O[(((size_t)nb * NH + hh) * SEQ + kq) * DH + d] =
                *(const bf16x8*)&smem[m_l * 136 + c8];
        }
    } else if (mode == 2) {  // V -> (n,h,d,k) via LDS transpose
#pragma unroll
        for (int mt = 0; mt < 4; ++mt)
#pragma unroll
            for (int nt = 0; nt < 4; ++nt)
#pragma unroll
                for (int reg = 0; reg < 4; ++reg) {
                    int m_l = wm * 64 + mt * 16 + quad * 4 + reg;
                    int c_l = wn * 64 + nt * 16 + l16;
                    smem[c_l * 136 + m_l] = f2bf(acc[mt][nt][reg] + bv4[nt]);
                }
        __syncthreads();
        unsigned short* O = (unsigned short*)C;
        int nb = m0g >> 11;
        int kq0 = m0g & (SEQ - 1);
#pragma unroll
        for (int j = 0; j < 8; ++j) {
            int i = tid + j * 256;
            int c_l = i >> 4, m8 = (i & 15) * 8;
            int cg = n0 + c_l, h = cg >> 6, d = cg & 63;
            *(bf16x8*)&O[(((size_t)nb * NH + h) * DH + d) * SEQ + kq0 + m8] =
                *(const bf16x8*)&smem[c_l * 136 + m8];
        }
    } else {  // OUT row-major, dual dtype
        unsigned short* Ob = (unsigned short*)C;
        float* Of = (float*)C;
#pragma unroll
        for (int mt = 0; mt < 4; ++mt)
#pragma unroll
            for (int reg = 0; reg < 4; ++reg) {
                int row = m0g + wm * 64 + mt * 16 + quad * 4 + reg;
#pragma unroll
                for (int nt = 0; nt < 4; ++nt) {
                    int c = n0 + wn * 64 + nt * 16 + l16;
                    float v = acc[mt][nt][reg] + bv4[nt];
                    if (isbf) Ob[(size_t)row * DMODEL + c] = f2bf(v);
                    else      Of[(size_t)row * DMODEL + c] = v;
                }
            }
    }
}

// ---------------------------------------------------------------------------
// MFMA flash attention — r17 (proven 60.0 us): triple buffer, DMA two tiles
// ahead, counted vmcnt(3), unroll-by-3 static buffer indices, setprio, XCD
// swizzle, ones-MFMA row-sum, launch_bounds(512,4).
// ---------------------------------------------------------------------------
__global__ __launch_bounds__(512, 4) void attn_mfma(
    const unsigned short* __restrict__ qws, const unsigned short* __restrict__ kws,
    const unsigned short* __restrict__ vtws, const unsigned int* __restrict__ mbits,
    unsigned short* __restrict__ yws)
{
    // XCD-aware remap (r13-proven): 64 blocks/XCD = 4 (n,h) x 16 qt.
    const int linear = blockIdx.x + (blockIdx.y << 4) + (blockIdx.z << 8);
    const int xcd = linear & 7, loc = linear >> 3;
    const int hn  = (xcd << 2) + (loc >> 4);   // 0..31
    const int qt  = loc & 15;
    const int h   = hn & 15;
    const int n   = hn >> 4;

    const int tid  = threadIdx.x;
    const int wave = tid >> 6;          // 0..7
    const int lane = tid & 63;
    const int l16  = lane & 15;
    const int quad = lane >> 4;

    __shared__ __align__(16) unsigned short Ks[3][BK * DH];    // [key][d], swizzled
    __shared__ __align__(16) unsigned short VTs[3][DH * BK];   // [d][key], swizzled
    __shared__ __align__(16) unsigned short Ps[8][16 * PAD];   // per-wave [qrow][key]

    const size_t base_nh = ((size_t)n * NH + h) * SEQ * DH;
    const size_t base_vt = ((size_t)n * NH + h) * DH * SEQ;
    const int q0 = qt * BQ;
    const int qrow = wave * 16 + l16;   // this lane's q-row within the block

    // mask-bit row pointer + Q fragments (prescaled QSCALE)
    const unsigned int* mr0 = mbits + ((size_t)n * SEQ + q0 + qrow) * (SEQ / 32);
    bf16x8 af[2];
    {
        const unsigned short* qp = qws + base_nh + (size_t)(q0 + qrow) * DH + quad * 8;
        af[0] = *(const bf16x8*)qp;
        af[1] = *(const bf16x8*)(qp + 32);
    }

    // DMA staging geometry + XOR swizzle (r9-proven). Each wave stages 8 rows
    // of K and 8 rows of V^T per tile (8 waves x 8 = 64 rows each).
    const int srow8  = lane >> 3;
    const int schunk = ((lane & 7) ^ srow8) * 8;
    const int swz = l16 & 7;
    int koff[2], voff[2];
#pragma unroll
    for (int ks = 0; ks < 2; ++ks) {
        koff[ks] = l16 * DH + (((ks * 4 + quad) ^ swz) * 8);
        voff[ks] = l16 * BK + (((ks * 4 + quad) ^ swz) * 8);
    }

    // ones B-fragment for the row-sum MFMA
    bf16x8 vones;
#pragma unroll
    for (int j = 0; j < 8; ++j) vones[j] = (__bf16)1.0f;

    // stage tile `t` into buffer slot `b` (2 VMEM ops/wave)
    auto stage = [&](int b, int t) {
        int j0t = t * BK;
        int rl = wave * 8;
        gl_lds16(&kws[base_nh + (size_t)(j0t + rl + srow8) * DH + schunk], &Ks[b][rl * DH]);
        gl_lds16(&vtws[base_vt + (size_t)(rl + srow8) * SEQ + j0t + schunk], &VTs[b][rl * BK]);
    };

    floatx4 O[4];
#pragma unroll
    for (int dt = 0; dt < 4; ++dt) O[dt] = floatx4{0.f, 0.f, 0.f, 0.f};
    floatx4 Lacc = floatx4{0.f, 0.f, 0.f, 0.f};

    // prologue: stage tiles 0 and 1; masks for tiles 0 (cur) and 1 (next)
    stage(0, 0);
    stage(1, 1);
    uint2 mwC = *(const uint2*)&mr0[0];
    uint2 mwN = *(const uint2*)&mr0[2];
    // one-time full drain (order-robust), then publish
    asm volatile("s_waitcnt vmcnt(0)" ::: "memory");
    __builtin_amdgcn_s_barrier();

    // one tile iteration. cb is ALWAYS a literal at call sites -> constant-
    // folded after inlining (static LDS bases). syncmode: 0 = vmcnt(3)+bar
    // (main), 1 = vmcnt(0)+bar (it=30), 2 = none (it=31).
    auto body = [&](int it, int cb, bool do_stage, int syncmode) {
        uint2 nA = {0, 0};
        if (do_stage) {
            int b2 = cb + 2; if (b2 >= 3) b2 -= 3;
            stage(b2, it + 2);
            nA = *(const uint2*)&mr0[(it + 2) * 2];
        }

        // ---- K·Q^T on buffer cb ----
        bf16x8 bfK[4][2];
#pragma unroll
        for (int nt = 0; nt < 4; ++nt)
#pragma unroll
            for (int ks = 0; ks < 2; ++ks)
                bfK[nt][ks] = *(const bf16x8*)&Ks[cb][nt * 16 * DH + koff[ks]];

        float St[4][4];
        __builtin_amdgcn_s_setprio(1);
#pragma unroll
        for (int nt = 0; nt < 4; ++nt) {
            floatx4 c = {0.f, 0.f, 0.f, 0.f};
            c = __builtin_amdgcn_mfma_f32_16x16x32_bf16(bfK[nt][0], af[0], c, 0, 0, 0);
            c = __builtin_amdgcn_mfma_f32_16x16x32_bf16(bfK[nt][1], af[1], c, 0, 0, 0);
            St[nt][0] = c[0]; St[nt][1] = c[1]; St[nt][2] = c[2]; St[nt][3] = c[3];
        }
        __builtin_amdgcn_s_setprio(0);

        // ---- p = bit ? 0 : exp2(s), RNE bf16 pack, b64 store ----
#pragma unroll
        for (int nt = 0; nt < 4; ++nt) {
            unsigned w = (nt & 2) ? mwC.y : mwC.x;
            int bb = (nt & 1) * 16 + quad * 4;
            float p[4];
#pragma unroll
            for (int r = 0; r < 4; ++r) {
                float e = __builtin_amdgcn_exp2f(St[nt][r]);
                p[r] = ((w >> (bb + r)) & 1u) ? 0.f : e;
            }
            bf16x2 e01, e23;
            e01[0] = (__bf16)p[0]; e01[1] = (__bf16)p[1];
            e23[0] = (__bf16)p[2]; e23[1] = (__bf16)p[3];
            uint2 pk;
            pk.x = *(unsigned*)&e01;
            pk.y = *(unsigned*)&e23;
            *(uint2*)&Ps[wave][l16 * PAD + nt * 16 + quad * 4] = pk;
        }

        // ---- PV + row-sum MFMA ----
        bf16x8 pa[2], vb[4][2];
#pragma unroll
        for (int ks = 0; ks < 2; ++ks)
            pa[ks] = *(const bf16x8*)&Ps[wave][l16 * PAD + ks * 32 + quad * 8];
#pragma unroll
        for (int dt = 0; dt < 4; ++dt)
#pragma unroll
            for (int ks = 0; ks < 2; ++ks)
                vb[dt][ks] = *(const bf16x8*)&VTs[cb][dt * 16 * BK + voff[ks]];

        __builtin_amdgcn_s_setprio(1);
        Lacc = __builtin_amdgcn_mfma_f32_16x16x32_bf16(pa[0], vones, Lacc, 0, 0, 0);
        Lacc = __builtin_amdgcn_mfma_f32_16x16x32_bf16(pa[1], vones, Lacc, 0, 0, 0);
#pragma unroll
        for (int dt = 0; dt < 4; ++dt) {
            O[dt] = __builtin_amdgcn_mfma_f32_16x16x32_bf16(pa[0], vb[dt][0], O[dt], 0, 0, 0);
            O[dt] = __builtin_amdgcn_mfma_f32_16x16x32_bf16(pa[1], vb[dt][1], O[dt], 0, 0, 0);
        }
        __builtin_amdgcn_s_setprio(0);

        if (syncmode == 0) {
            asm volatile("s_waitcnt vmcnt(3)" ::: "memory");
            __builtin_amdgcn_s_barrier();
        } else if (syncmode == 1) {
            asm volatile("s_waitcnt vmcnt(0)" ::: "memory");
            __builtin_amdgcn_s_barrier();
        }
        mwC = mwN;
        mwN = nA;
    };

    // main: 30 uniform iterations as 10 triples with static buffer index.
    for (int t3 = 0; t3 < 30; t3 += 3) {
        body(t3 + 0, 0, true, 0);
        body(t3 + 1, 1, true, 0);
        body(t3 + 2, 2, true, 0);
    }
    body(30, 0, false, 1);   // consumes buf 0 (staged at it=28); full drain
    body(31, 1, false, 2);   // last tile, no sync needed

    // epilogue: Lacc holds full row-sums in (quad*4+r) layout
#pragma unroll
    for (int r = 0; r < 4; ++r) {
        float lr = Lacc[r];
        float inv = (lr > 0.f) ? 1.f / lr : 0.f;
        int row = q0 + wave * 16 + quad * 4 + r;
#pragma unroll
        for (int dt = 0; dt < 4; ++dt) {
            int col = h * DH + dt * 16 + l16;
            yws[((size_t)n * SEQ + row) * DMODEL + col] = f2bf(O[dt][r] * inv);
        }
    }
}

extern "C" void kernel_launch(void* const* d_in, const int* in_sizes, int n_in,
                              void* d_out, int out_size, void* d_ws, size_t ws_size,
                              hipStream_t stream) {
    const void* query = d_in[0];
    const void* key_  = d_in[1];
    const void* value = d_in[2];
    const void* mask  = d_in[3];
    const void* Wq = d_in[4];
    const void* bq = d_in[5];
    const void* Wk = d_in[6];
    const void* bk = d_in[7];
    const void* Wv = d_in[8];
    const void* bv = d_in[9];
    const void* Wp = d_in[10];
    const void* bp = d_in[11];

    const size_t per = (size_t)NB * NH * SEQ * DH;  // 4,194,304
    unsigned short* us = (unsigned short*)d_ws;
    unsigned short* qws  = us;
    unsigned short* kws  = us + per;
    unsigned short* vtws = us + 2 * per;
    unsigned short* abf0 = us + 3 * per;   // bf16 query acts; reused as yws after proj
    unsigned short* abf1 = us + 4 * per;
    unsigned short* abf2 = us + 5 * per;
    unsigned short* wt0  = us + 6 * per;
    unsigned short* wt1  = wt0 + 1048576;
    unsigned short* wt2  = wt1 + 1048576;
    unsigned short* wt3  = wt2 + 1048576;
    unsigned int* mbits  = (unsigned int*)(wt3 + 1048576);  // 262144 words
    unsigned short* yws = abf0;

    prep<<<dim3(14336), 256, 0, stream>>>(query, key_, value, mask,
                                          Wq, Wk, Wv, Wp,
                                          abf0, abf1, abf2,
                                          wt0, wt1, wt2, wt3, mbits);
    gemm_mfma<<<dim3(8, 32, 3), 256, 0, stream>>>(abf0, abf1, abf2, wt0, wt1, wt2,
                                                  bq, bk, bv, qws, kws, vtws, 0);
    attn_mfma<<<dim3(SEQ / BQ, NH, NB), 512, 0, stream>>>(qws, kws, vtws, mbits, yws);
    gemm_mfma<<<dim3(8, 32, 1), 256, 0, stream>>>(yws, yws, yws, wt3, wt3, wt3,
                                                  bp, bp, bp, d_out, d_out, d_out, 3);
}